// Round 3
// baseline (235.009 us; speedup 1.0000x reference)
//
#include <hip/hip_runtime.h>
#include <hip/hip_bf16.h>
#include <math.h>

#define B_ 4
#define DIM_ 256
#define H_ 128
#define W_ 128
#define HW_ (H_ * W_)
#define AD_ 64
#define HEADS_ 4
#define HD_ 16
#define WS_ 5
#define PAD_ 2

// ---------------- weight transpose: (O,C) row-major -> (C,O) c-major ----------
__global__ __launch_bounds__(256) void k_transpose_w(
    const float* __restrict__ Wq, const float* __restrict__ Wk,
    const float* __restrict__ Wv, const float* __restrict__ Wo,
    float* __restrict__ WqT, float* __restrict__ WkT,
    float* __restrict__ WvT, float* __restrict__ WoT)
{
    int i = blockIdx.x * blockDim.x + threadIdx.x;
    if (i >= AD_ * DIM_) return;
    // Wq/Wk/Wv: (64,256) -> (256,64)
    int o = i / DIM_, c = i % DIM_;
    WqT[c * AD_ + o] = Wq[i];
    WkT[c * AD_ + o] = Wk[i];
    WvT[c * AD_ + o] = Wv[i];
    // Wo: (256,64) -> (64,256)
    int o2 = i / AD_, c2 = i % AD_;
    WoT[c2 * DIM_ + o2] = Wo[i];
}

// ---------------- QKV projection v3: LDS-resident weights ---------------------
// Block = 256 threads = 4 waves, ALL computing the SAME (type, head) over 512
// consecutive pixels (2 px/lane). The head's 256x16 weight slice (16 KB) is
// staged in LDS once and read per-c as 4 uniform-address ds_read_b128
// broadcasts — removes the per-wave scalar-cache weight stream (12 distinct
// 16KB s_load streams thrashing the 16KB K$ was the correlated stall).
// grid = 3 types * 4 heads * 128 groups = 1536 blocks -> ~24 waves/CU.
// FMA order over c per output unchanged -> identical results.
__global__ __launch_bounds__(256) void k_qkv(
    const float* __restrict__ q_in, const float* __restrict__ kv_in,
    const float* __restrict__ WqT, const float* __restrict__ WkT,
    const float* __restrict__ WvT,
    float* __restrict__ qh, float* __restrict__ kh, float* __restrict__ vv)
{
    __shared__ float4 Wl[DIM_ * HD_ / 4];     // 16 KB: Wl[c*4+q] = W[c][4q..4q+3]

    int bid = blockIdx.x;
    int g   = bid / 12;                       // pixel group 0..127
    int th  = bid % 12;
    int t   = th >> 2;                        // 0=Q 1=K 2=V
    int h   = th & 3;                         // head

    const float* src = (t == 0) ? q_in : kv_in;
    const float* WT  = (t == 0) ? WqT : (t == 1) ? WkT : WvT;
    float* dstb      = (t == 0) ? qh  : (t == 1) ? kh  : vv;

    // stage this head's weight slice: 1024 float4s, 4 per thread
    const float4* WT4 = (const float4*)WT;    // WT4[c*16 + hh*4 + q]
    int tid = threadIdx.x;
#pragma unroll
    for (int k = 0; k < 4; ++k) {
        int idx = tid + k * 256;              // 0..1023
        int c = idx >> 2, q = idx & 3;
        Wl[idx] = WT4[c * 16 + h * 4 + q];
    }
    __syncthreads();

    int pix = g * 512 + tid * 2;              // 2 consecutive pixels
    int b = pix >> 14;                        // uniform per block
    int p = pix & (HW_ - 1);
    const float* xp = src + (size_t)b * DIM_ * HW_ + p;

    float acc0[HD_], acc1[HD_];
#pragma unroll
    for (int d = 0; d < HD_; ++d) { acc0[d] = 0.f; acc1[d] = 0.f; }

#pragma unroll 4
    for (int c = 0; c < DIM_; ++c) {
        float2 xv = *(const float2*)(xp + (size_t)c * HW_);  // coalesced 8B/lane
        float4 w0 = Wl[c * 4 + 0];            // uniform addr -> LDS broadcast
        float4 w1 = Wl[c * 4 + 1];
        float4 w2 = Wl[c * 4 + 2];
        float4 w3 = Wl[c * 4 + 3];
        const float wr[HD_] = { w0.x, w0.y, w0.z, w0.w, w1.x, w1.y, w1.z, w1.w,
                                w2.x, w2.y, w2.z, w2.w, w3.x, w3.y, w3.z, w3.w };
#pragma unroll
        for (int d = 0; d < HD_; ++d) {
            acc0[d] = fmaf(wr[d], xv.x, acc0[d]);
            acc1[d] = fmaf(wr[d], xv.y, acc1[d]);
        }
    }

    if (t < 2) {                              // l2-normalize (Q and K)
        float s0 = 0.f, s1 = 0.f;
#pragma unroll
        for (int d = 0; d < HD_; ++d) {
            s0 = fmaf(acc0[d], acc0[d], s0);
            s1 = fmaf(acc1[d], acc1[d], s1);
        }
        float inv0 = 1.f / fmaxf(sqrtf(s0), 1e-12f);
        float inv1 = 1.f / fmaxf(sqrtf(s1), 1e-12f);
#pragma unroll
        for (int d = 0; d < HD_; ++d) { acc0[d] *= inv0; acc1[d] *= inv1; }
    }

    float* dst = dstb + (((size_t)b * HEADS_ + h) * HW_ + p) * HD_;
    *(float4*)(dst + 0)  = make_float4(acc0[0],  acc0[1],  acc0[2],  acc0[3]);
    *(float4*)(dst + 4)  = make_float4(acc0[4],  acc0[5],  acc0[6],  acc0[7]);
    *(float4*)(dst + 8)  = make_float4(acc0[8],  acc0[9],  acc0[10], acc0[11]);
    *(float4*)(dst + 12) = make_float4(acc0[12], acc0[13], acc0[14], acc0[15]);
    *(float4*)(dst + 16) = make_float4(acc1[0],  acc1[1],  acc1[2],  acc1[3]);
    *(float4*)(dst + 20) = make_float4(acc1[4],  acc1[5],  acc1[6],  acc1[7]);
    *(float4*)(dst + 24) = make_float4(acc1[8],  acc1[9],  acc1[10], acc1[11]);
    *(float4*)(dst + 28) = make_float4(acc1[12], acc1[13], acc1[14], acc1[15]);
}

__device__ __forceinline__ int refl(int i, int n) {
    if (i < 0) i = -i;
    if (i >= n) i = 2 * n - 2 - i;
    return i;
}

// ---------------- sliding-window attention: one thread per (b,head,pixel) ----
__global__ __launch_bounds__(256) void k_attn(
    const float* __restrict__ qh, const float* __restrict__ kh,
    const float* __restrict__ vv, float* __restrict__ ao)
{
    int gid = blockIdx.x * blockDim.x + threadIdx.x;   // (b*4+h)*HW + p
    int p  = gid & (HW_ - 1);
    int bh = gid >> 14;
    int y = p >> 7, x = p & (W_ - 1);

    const float* qp = qh + ((size_t)bh * HW_ + p) * HD_;
    float4 q0 = *(const float4*)(qp + 0);
    float4 q1 = *(const float4*)(qp + 4);
    float4 q2 = *(const float4*)(qp + 8);
    float4 q3 = *(const float4*)(qp + 12);

    float logit[WS_ * WS_];
    int   nidx [WS_ * WS_];
#pragma unroll
    for (int i = 0; i < WS_; ++i) {
        int ry = refl(y + i - PAD_, H_);
#pragma unroll
        for (int j = 0; j < WS_; ++j) {
            int rx = refl(x + j - PAD_, W_);
            int np_ = ry * W_ + rx;
            nidx[i*WS_ + j] = np_;
            const float* kp = kh + ((size_t)bh * HW_ + np_) * HD_;
            float4 ka = *(const float4*)(kp + 0);
            float4 kb = *(const float4*)(kp + 4);
            float4 kc = *(const float4*)(kp + 8);
            float4 kd = *(const float4*)(kp + 12);
            float d = 0.f;
            d = fmaf(q0.x, ka.x, d); d = fmaf(q0.y, ka.y, d);
            d = fmaf(q0.z, ka.z, d); d = fmaf(q0.w, ka.w, d);
            d = fmaf(q1.x, kb.x, d); d = fmaf(q1.y, kb.y, d);
            d = fmaf(q1.z, kb.z, d); d = fmaf(q1.w, kb.w, d);
            d = fmaf(q2.x, kc.x, d); d = fmaf(q2.y, kc.y, d);
            d = fmaf(q2.z, kc.z, d); d = fmaf(q2.w, kc.w, d);
            d = fmaf(q3.x, kd.x, d); d = fmaf(q3.y, kd.y, d);
            d = fmaf(q3.z, kd.z, d); d = fmaf(q3.w, kd.w, d);
            logit[i*WS_ + j] = d;
        }
    }

    float m = logit[0];
#pragma unroll
    for (int w = 1; w < WS_*WS_; ++w) m = fmaxf(m, logit[w]);
    float s = 0.f;
#pragma unroll
    for (int w = 0; w < WS_*WS_; ++w) { float e = expf(logit[w] - m); logit[w] = e; s += e; }
    float invs = 1.f / s;

    float a[HD_];
#pragma unroll
    for (int d = 0; d < HD_; ++d) a[d] = 0.f;
#pragma unroll
    for (int w = 0; w < WS_*WS_; ++w) {
        float wt = logit[w] * invs;
        const float* vp = vv + ((size_t)bh * HW_ + nidx[w]) * HD_;
        float4 va = *(const float4*)(vp + 0);
        float4 vb = *(const float4*)(vp + 4);
        float4 vc = *(const float4*)(vp + 8);
        float4 vd = *(const float4*)(vp + 12);
        a[0]  = fmaf(wt, va.x, a[0]);  a[1]  = fmaf(wt, va.y, a[1]);
        a[2]  = fmaf(wt, va.z, a[2]);  a[3]  = fmaf(wt, va.w, a[3]);
        a[4]  = fmaf(wt, vb.x, a[4]);  a[5]  = fmaf(wt, vb.y, a[5]);
        a[6]  = fmaf(wt, vb.z, a[6]);  a[7]  = fmaf(wt, vb.w, a[7]);
        a[8]  = fmaf(wt, vc.x, a[8]);  a[9]  = fmaf(wt, vc.y, a[9]);
        a[10] = fmaf(wt, vc.z, a[10]); a[11] = fmaf(wt, vc.w, a[11]);
        a[12] = fmaf(wt, vd.x, a[12]); a[13] = fmaf(wt, vd.y, a[13]);
        a[14] = fmaf(wt, vd.z, a[14]); a[15] = fmaf(wt, vd.w, a[15]);
    }

    int b = bh >> 2, h = bh & 3;
    float* aop = ao + ((size_t)b * HW_ + p) * AD_ + h * HD_;
    *(float4*)(aop + 0)  = make_float4(a[0],  a[1],  a[2],  a[3]);
    *(float4*)(aop + 4)  = make_float4(a[4],  a[5],  a[6],  a[7]);
    *(float4*)(aop + 8)  = make_float4(a[8],  a[9],  a[10], a[11]);
    *(float4*)(aop + 12) = make_float4(a[12], a[13], a[14], a[15]);
}

// ---------------- output projection: out[b, oc, p] = sum_c WoT[c][oc] * ao[b,p,c]
__global__ __launch_bounds__(256) void k_oproj(
    const float* __restrict__ ao, const float* __restrict__ WoT,
    float* __restrict__ out)
{
    int lane = threadIdx.x & 63;
    int och  = __builtin_amdgcn_readfirstlane((int)(threadIdx.x >> 6)); // 0..3, SGPR
    int pix  = blockIdx.x * 64 + lane;                                  // 0..65535
    int b = pix >> 14;
    int p = pix & (HW_ - 1);
    const float* xp = ao + (size_t)pix * AD_;

    float acc[64];
#pragma unroll
    for (int o = 0; o < 64; ++o) acc[o] = 0.f;

    for (int c4 = 0; c4 < AD_ / 4; ++c4) {
        float4 xv = *(const float4*)(xp + c4 * 4);
#pragma unroll
        for (int cc = 0; cc < 4; ++cc) {
            float xs = (cc == 0) ? xv.x : (cc == 1) ? xv.y : (cc == 2) ? xv.z : xv.w;
            const float* wr = WoT + (size_t)(c4*4 + cc) * DIM_ + och * 64;  // uniform -> s_load
#pragma unroll
            for (int o = 0; o < 64; ++o) acc[o] = fmaf(wr[o], xs, acc[o]);
        }
    }

    float* op = out + (size_t)b * DIM_ * HW_ + (size_t)och * 64 * HW_ + p;
#pragma unroll
    for (int o = 0; o < 64; ++o) op[(size_t)o * HW_] = acc[o];
}

extern "C" void kernel_launch(void* const* d_in, const int* in_sizes, int n_in,
                              void* d_out, int out_size, void* d_ws, size_t ws_size,
                              hipStream_t stream) {
    const float* q_in  = (const float*)d_in[0];
    const float* kv_in = (const float*)d_in[1];
    const float* Wq    = (const float*)d_in[2];
    const float* Wk    = (const float*)d_in[3];
    const float* Wv    = (const float*)d_in[4];
    const float* Wo    = (const float*)d_in[5];
    float* out = (float*)d_out;

    float* wsf = (float*)d_ws;
    float* WqT = wsf;
    float* WkT = WqT + AD_ * DIM_;
    float* WvT = WkT + AD_ * DIM_;
    float* WoT = WvT + AD_ * DIM_;
    size_t tens = (size_t)B_ * HEADS_ * HW_ * HD_;   // 4,194,304 floats
    float* qh = WoT + AD_ * DIM_;
    float* kh = qh + tens;
    float* vv = kh + tens;
    float* ao = vv + tens;

    k_transpose_w<<<dim3(64), dim3(256), 0, stream>>>(Wq, Wk, Wv, Wo, WqT, WkT, WvT, WoT);
    k_qkv<<<dim3(1536), dim3(256), 0, stream>>>(q_in, kv_in, WqT, WkT, WvT, qh, kh, vv);
    k_attn <<<dim3(1024), dim3(256), 0, stream>>>(qh, kh, vv, ao);
    k_oproj<<<dim3(1024), dim3(256), 0, stream>>>(ao, WoT, out);
}

// Round 4
// 219.520 us; speedup vs baseline: 1.0706x; 1.0706x over previous
//
#include <hip/hip_runtime.h>
#include <hip/hip_bf16.h>
#include <math.h>

#define B_ 4
#define DIM_ 256
#define H_ 128
#define W_ 128
#define HW_ (H_ * W_)
#define AD_ 64
#define HEADS_ 4
#define HD_ 16
#define WS_ 5
#define PAD_ 2
#define CH_ 32   // c-chunk staged in LDS per iteration

// ---------------- weight transpose: (O,C) row-major -> (C,O) c-major ----------
__global__ __launch_bounds__(256) void k_transpose_w(
    const float* __restrict__ Wq, const float* __restrict__ Wk,
    const float* __restrict__ Wv, const float* __restrict__ Wo,
    float* __restrict__ WqT, float* __restrict__ WkT,
    float* __restrict__ WvT, float* __restrict__ WoT)
{
    int i = blockIdx.x * blockDim.x + threadIdx.x;
    if (i >= AD_ * DIM_) return;
    // Wq/Wk/Wv: (64,256) -> (256,64)
    int o = i / DIM_, c = i % DIM_;
    WqT[c * AD_ + o] = Wq[i];
    WkT[c * AD_ + o] = Wk[i];
    WvT[c * AD_ + o] = Wv[i];
    // Wo: (256,64) -> (64,256)
    int o2 = i / AD_, c2 = i % AD_;
    WoT[c2 * DIM_ + o2] = Wo[i];
}

// ---------------- QKV projection v4: c-chunked LDS GEMM -----------------------
// Block = 768 threads = 12 waves (t,h) over the SAME 128 pixels (2 px/lane)
// -> input fetched once (R2's 67 MB), unlike R3's per-head blocks (393 MB).
// Per 32-c chunk: cooperatively stage W tile (3*32*64 f32 = 24 KB) and x tile
// (2 srcs * 32c * 128px = 32 KB), barrier, then inner loop reads x via
// ds_read_b64 (2-way bank alias = free) and weights via uniform-broadcast
// ds_read_b128. No per-c global load, no per-c scalar stream -> the ~500cy
// per-iteration lockstep stall seen in R0-R3 is paid once per chunk.
// LDS 56 KB -> 2 blocks/CU = 24 waves/CU. FMA order over c unchanged.
__global__ __launch_bounds__(768) void k_qkv(
    const float* __restrict__ q_in, const float* __restrict__ kv_in,
    const float* __restrict__ WqT, const float* __restrict__ WkT,
    const float* __restrict__ WvT,
    float* __restrict__ qh, float* __restrict__ kh, float* __restrict__ vv)
{
    __shared__ float4 Wl4[3 * CH_ * 16];   // [t][cl][16 float4] = 24 KB
    __shared__ float4 Xl4[2 * CH_ * 32];   // [src][cl][32 float4] = 32 KB

    int tid  = threadIdx.x;
    int lane = tid & 63;
    int w    = __builtin_amdgcn_readfirstlane(tid >> 6); // 0..11
    int t    = w >> 2;                     // 0=Q 1=K 2=V
    int h    = w & 3;                      // head
    int g    = blockIdx.x;                 // 128-pixel group
    int b    = g >> 7;                     // batch (128 groups per batch)
    int p0   = (g & 127) * 128;            // pixel base within batch

    int s = (t == 0) ? 0 : 1;              // which x slice this wave consumes
    float* dstb = (t == 0) ? qh : (t == 1) ? kh : vv;

    float acc0[HD_], acc1[HD_];
#pragma unroll
    for (int d = 0; d < HD_; ++d) { acc0[d] = 0.f; acc1[d] = 0.f; }

    for (int c0 = 0; c0 < DIM_; c0 += CH_) {
        __syncthreads();                   // protect prev chunk's reads
        // ---- stage W: 3*CH_*16 = 1536 float4, 2 per thread
#pragma unroll
        for (int k = 0; k < 2; ++k) {
            int idx = tid + k * 768;       // 0..1535
            int ts = idx / 512, rem = idx & 511;
            int cl = rem >> 4, q = rem & 15;
            const float4* Wsrc = (const float4*)((ts == 0) ? WqT : (ts == 1) ? WkT : WvT);
            Wl4[idx] = Wsrc[(c0 + cl) * 16 + q];
        }
        // ---- stage X: 2*CH_*32 = 2048 float4, <=3 per thread
#pragma unroll
        for (int k = 0; k < 3; ++k) {
            int idx = tid + k * 768;
            if (idx < 2048) {
                int ss = idx >> 10, rem = idx & 1023;
                int cl = rem >> 5, q = rem & 31;
                const float* xs = ss ? kv_in : q_in;
                Xl4[idx] = ((const float4*)(xs + ((size_t)(b * DIM_ + c0 + cl)) * HW_ + p0))[q];
            }
        }
        __syncthreads();

        const float2* Xrow = (const float2*)&Xl4[s * (CH_ * 32)]; // [CH_][64] float2
#pragma unroll 8
        for (int cl = 0; cl < CH_; ++cl) {
            float2 xv = Xrow[cl * 64 + lane];                 // 2-way alias, free
            float4 w0 = Wl4[(t * CH_ + cl) * 16 + h * 4 + 0]; // uniform -> broadcast
            float4 w1 = Wl4[(t * CH_ + cl) * 16 + h * 4 + 1];
            float4 w2 = Wl4[(t * CH_ + cl) * 16 + h * 4 + 2];
            float4 w3 = Wl4[(t * CH_ + cl) * 16 + h * 4 + 3];
            const float wr[HD_] = { w0.x, w0.y, w0.z, w0.w, w1.x, w1.y, w1.z, w1.w,
                                    w2.x, w2.y, w2.z, w2.w, w3.x, w3.y, w3.z, w3.w };
#pragma unroll
            for (int d = 0; d < HD_; ++d) {
                acc0[d] = fmaf(wr[d], xv.x, acc0[d]);
                acc1[d] = fmaf(wr[d], xv.y, acc1[d]);
            }
        }
    }

    if (t < 2) {                           // l2-normalize (Q and K), wave-uniform
        float s0 = 0.f, s1 = 0.f;
#pragma unroll
        for (int d = 0; d < HD_; ++d) {
            s0 = fmaf(acc0[d], acc0[d], s0);
            s1 = fmaf(acc1[d], acc1[d], s1);
        }
        float inv0 = 1.f / fmaxf(sqrtf(s0), 1e-12f);
        float inv1 = 1.f / fmaxf(sqrtf(s1), 1e-12f);
#pragma unroll
        for (int d = 0; d < HD_; ++d) { acc0[d] *= inv0; acc1[d] *= inv1; }
    }

    int p = p0 + lane * 2;
    float* dst = dstb + (((size_t)b * HEADS_ + h) * HW_ + p) * HD_;
    *(float4*)(dst + 0)  = make_float4(acc0[0],  acc0[1],  acc0[2],  acc0[3]);
    *(float4*)(dst + 4)  = make_float4(acc0[4],  acc0[5],  acc0[6],  acc0[7]);
    *(float4*)(dst + 8)  = make_float4(acc0[8],  acc0[9],  acc0[10], acc0[11]);
    *(float4*)(dst + 12) = make_float4(acc0[12], acc0[13], acc0[14], acc0[15]);
    *(float4*)(dst + 16) = make_float4(acc1[0],  acc1[1],  acc1[2],  acc1[3]);
    *(float4*)(dst + 20) = make_float4(acc1[4],  acc1[5],  acc1[6],  acc1[7]);
    *(float4*)(dst + 24) = make_float4(acc1[8],  acc1[9],  acc1[10], acc1[11]);
    *(float4*)(dst + 28) = make_float4(acc1[12], acc1[13], acc1[14], acc1[15]);
}

__device__ __forceinline__ int refl(int i, int n) {
    if (i < 0) i = -i;
    if (i >= n) i = 2 * n - 2 - i;
    return i;
}

// ---------------- sliding-window attention: one thread per (b,head,pixel) ----
__global__ __launch_bounds__(256) void k_attn(
    const float* __restrict__ qh, const float* __restrict__ kh,
    const float* __restrict__ vv, float* __restrict__ ao)
{
    int gid = blockIdx.x * blockDim.x + threadIdx.x;   // (b*4+h)*HW + p
    int p  = gid & (HW_ - 1);
    int bh = gid >> 14;
    int y = p >> 7, x = p & (W_ - 1);

    const float* qp = qh + ((size_t)bh * HW_ + p) * HD_;
    float4 q0 = *(const float4*)(qp + 0);
    float4 q1 = *(const float4*)(qp + 4);
    float4 q2 = *(const float4*)(qp + 8);
    float4 q3 = *(const float4*)(qp + 12);

    float logit[WS_ * WS_];
    int   nidx [WS_ * WS_];
#pragma unroll
    for (int i = 0; i < WS_; ++i) {
        int ry = refl(y + i - PAD_, H_);
#pragma unroll
        for (int j = 0; j < WS_; ++j) {
            int rx = refl(x + j - PAD_, W_);
            int np_ = ry * W_ + rx;
            nidx[i*WS_ + j] = np_;
            const float* kp = kh + ((size_t)bh * HW_ + np_) * HD_;
            float4 ka = *(const float4*)(kp + 0);
            float4 kb = *(const float4*)(kp + 4);
            float4 kc = *(const float4*)(kp + 8);
            float4 kd = *(const float4*)(kp + 12);
            float d = 0.f;
            d = fmaf(q0.x, ka.x, d); d = fmaf(q0.y, ka.y, d);
            d = fmaf(q0.z, ka.z, d); d = fmaf(q0.w, ka.w, d);
            d = fmaf(q1.x, kb.x, d); d = fmaf(q1.y, kb.y, d);
            d = fmaf(q1.z, kb.z, d); d = fmaf(q1.w, kb.w, d);
            d = fmaf(q2.x, kc.x, d); d = fmaf(q2.y, kc.y, d);
            d = fmaf(q2.z, kc.z, d); d = fmaf(q2.w, kc.w, d);
            d = fmaf(q3.x, kd.x, d); d = fmaf(q3.y, kd.y, d);
            d = fmaf(q3.z, kd.z, d); d = fmaf(q3.w, kd.w, d);
            logit[i*WS_ + j] = d;
        }
    }

    float m = logit[0];
#pragma unroll
    for (int w = 1; w < WS_*WS_; ++w) m = fmaxf(m, logit[w]);
    float s = 0.f;
#pragma unroll
    for (int w = 0; w < WS_*WS_; ++w) { float e = expf(logit[w] - m); logit[w] = e; s += e; }
    float invs = 1.f / s;

    float a[HD_];
#pragma unroll
    for (int d = 0; d < HD_; ++d) a[d] = 0.f;
#pragma unroll
    for (int w = 0; w < WS_*WS_; ++w) {
        float wt = logit[w] * invs;
        const float* vp = vv + ((size_t)bh * HW_ + nidx[w]) * HD_;
        float4 va = *(const float4*)(vp + 0);
        float4 vb = *(const float4*)(vp + 4);
        float4 vc = *(const float4*)(vp + 8);
        float4 vd = *(const float4*)(vp + 12);
        a[0]  = fmaf(wt, va.x, a[0]);  a[1]  = fmaf(wt, va.y, a[1]);
        a[2]  = fmaf(wt, va.z, a[2]);  a[3]  = fmaf(wt, va.w, a[3]);
        a[4]  = fmaf(wt, vb.x, a[4]);  a[5]  = fmaf(wt, vb.y, a[5]);
        a[6]  = fmaf(wt, vb.z, a[6]);  a[7]  = fmaf(wt, vb.w, a[7]);
        a[8]  = fmaf(wt, vc.x, a[8]);  a[9]  = fmaf(wt, vc.y, a[9]);
        a[10] = fmaf(wt, vc.z, a[10]); a[11] = fmaf(wt, vc.w, a[11]);
        a[12] = fmaf(wt, vd.x, a[12]); a[13] = fmaf(wt, vd.y, a[13]);
        a[14] = fmaf(wt, vd.z, a[14]); a[15] = fmaf(wt, vd.w, a[15]);
    }

    int b = bh >> 2, h = bh & 3;
    float* aop = ao + ((size_t)b * HW_ + p) * AD_ + h * HD_;
    *(float4*)(aop + 0)  = make_float4(a[0],  a[1],  a[2],  a[3]);
    *(float4*)(aop + 4)  = make_float4(a[4],  a[5],  a[6],  a[7]);
    *(float4*)(aop + 8)  = make_float4(a[8],  a[9],  a[10], a[11]);
    *(float4*)(aop + 12) = make_float4(a[12], a[13], a[14], a[15]);
}

// ---------------- output projection: out[b, oc, p] = sum_c WoT[c][oc] * ao[b,p,c]
__global__ __launch_bounds__(256) void k_oproj(
    const float* __restrict__ ao, const float* __restrict__ WoT,
    float* __restrict__ out)
{
    int lane = threadIdx.x & 63;
    int och  = __builtin_amdgcn_readfirstlane((int)(threadIdx.x >> 6)); // 0..3, SGPR
    int pix  = blockIdx.x * 64 + lane;                                  // 0..65535
    int b = pix >> 14;
    int p = pix & (HW_ - 1);
    const float* xp = ao + (size_t)pix * AD_;

    float acc[64];
#pragma unroll
    for (int o = 0; o < 64; ++o) acc[o] = 0.f;

    for (int c4 = 0; c4 < AD_ / 4; ++c4) {
        float4 xv = *(const float4*)(xp + c4 * 4);
#pragma unroll
        for (int cc = 0; cc < 4; ++cc) {
            float xs = (cc == 0) ? xv.x : (cc == 1) ? xv.y : (cc == 2) ? xv.z : xv.w;
            const float* wr = WoT + (size_t)(c4*4 + cc) * DIM_ + och * 64;  // uniform -> s_load
#pragma unroll
            for (int o = 0; o < 64; ++o) acc[o] = fmaf(wr[o], xs, acc[o]);
        }
    }

    float* op = out + (size_t)b * DIM_ * HW_ + (size_t)och * 64 * HW_ + p;
#pragma unroll
    for (int o = 0; o < 64; ++o) op[(size_t)o * HW_] = acc[o];
}

extern "C" void kernel_launch(void* const* d_in, const int* in_sizes, int n_in,
                              void* d_out, int out_size, void* d_ws, size_t ws_size,
                              hipStream_t stream) {
    const float* q_in  = (const float*)d_in[0];
    const float* kv_in = (const float*)d_in[1];
    const float* Wq    = (const float*)d_in[2];
    const float* Wk    = (const float*)d_in[3];
    const float* Wv    = (const float*)d_in[4];
    const float* Wo    = (const float*)d_in[5];
    float* out = (float*)d_out;

    float* wsf = (float*)d_ws;
    float* WqT = wsf;
    float* WkT = WqT + AD_ * DIM_;
    float* WvT = WkT + AD_ * DIM_;
    float* WoT = WvT + AD_ * DIM_;
    size_t tens = (size_t)B_ * HEADS_ * HW_ * HD_;   // 4,194,304 floats
    float* qh = WoT + AD_ * DIM_;
    float* kh = qh + tens;
    float* vv = kh + tens;
    float* ao = vv + tens;

    k_transpose_w<<<dim3(64), dim3(256), 0, stream>>>(Wq, Wk, Wv, Wo, WqT, WkT, WvT, WoT);
    k_qkv<<<dim3(512), dim3(768), 0, stream>>>(q_in, kv_in, WqT, WkT, WvT, qh, kh, vv);
    k_attn <<<dim3(1024), dim3(256), 0, stream>>>(qh, kh, vv, ao);
    k_oproj<<<dim3(1024), dim3(256), 0, stream>>>(ao, WoT, out);
}

// Round 5
// 168.340 us; speedup vs baseline: 1.3960x; 1.3040x over previous
//
#include <hip/hip_runtime.h>
#include <hip/hip_bf16.h>
#include <math.h>

#define B_ 4
#define DIM_ 256
#define H_ 128
#define W_ 128
#define HW_ (H_ * W_)
#define AD_ 64
#define HEADS_ 4
#define HD_ 16
#define WS_ 5
#define PAD_ 2

typedef __attribute__((ext_vector_type(8))) short short8;
typedef __attribute__((ext_vector_type(4))) float f32x4;

__device__ __forceinline__ ushort f2bf(float f) {
    unsigned u = __builtin_bit_cast(unsigned, f);
    unsigned r = u + 0x7FFFu + ((u >> 16) & 1u);
    return (ushort)(r >> 16);
}
__device__ __forceinline__ float bf2f(ushort h) {
    return __builtin_bit_cast(float, (unsigned)h << 16);
}

// ---------------- prep: WoT for oproj + fragment-ordered bf16 hi/lo weights --
// A-fragment layout for mfma_f32_16x16x32_bf16: lane l holds A[o=l&15][c] for
// 8 c's = kc*32 + (l>>4)*8 + j. The SAME (lane,j)->c map is used for the B
// gather in k_qkv, so the contraction is correct under any consistent k-perm.
__global__ __launch_bounds__(256) void k_prep(
    const float* __restrict__ Wq, const float* __restrict__ Wk,
    const float* __restrict__ Wv, const float* __restrict__ Wo,
    ushort* __restrict__ WfQh, ushort* __restrict__ WfQl,
    ushort* __restrict__ WfKVh, ushort* __restrict__ WfKVl,
    float* __restrict__ WoT)
{
    int i = blockIdx.x * 256 + threadIdx.x;          // 0 .. 49151
    if (i < AD_ * DIM_) {                            // WoT: (256,64) -> (64,256)
        int o2 = i / AD_, c2 = i % AD_;
        WoT[c2 * DIM_ + o2] = Wo[i];
    }
    if (i < 16384) {                                 // Q frags: 4mt*8kc*64l*8j
        int j = i & 7, l = (i >> 3) & 63, kc = (i >> 9) & 7, mt = i >> 12;
        int o = mt * 16 + (l & 15);
        int c = kc * 32 + ((l >> 4) & 3) * 8 + j;
        float wv = Wq[o * DIM_ + c];
        ushort h = f2bf(wv);
        WfQh[i] = h;
        WfQl[i] = f2bf(wv - bf2f(h));
    } else if (i < 49152) {                          // KV frags: 8mt (K:0-3, V:4-7)
        int ii = i - 16384;
        int j = ii & 7, l = (ii >> 3) & 63, kc = (ii >> 9) & 7, mt = ii >> 12;
        const float* Ws = (mt < 4) ? Wk : Wv;
        int o = (mt & 3) * 16 + (l & 15);
        int c = kc * 32 + ((l >> 4) & 3) * 8 + j;
        float wv = Ws[o * DIM_ + c];
        ushort h = f2bf(wv);
        WfKVh[ii] = h;
        WfKVl[ii] = f2bf(wv - bf2f(h));
    }
}

// ---------------- QKV projection v5: bf16x3 MFMA, no LDS, no barriers --------
// Wave tile: M = MT*16 outputs x N = 32 pixels, K = 256 in 8 chunks of 32.
// B-frag gathered per-lane from global f32 x, split hi/lo in registers.
// A-frag loaded fragment-ordered from L2-hot precomputed arrays.
// acc += Ahi*Bhi + Ahi*Blo + Alo*Bhi  (f32 accumulate, err ~1e-5 rel).
// D layout (verified): col = lane&15, row = 4*(lane>>4) + reg.
template<int MT, int NORM_MT>
__device__ __forceinline__ void proj_mfma(
    const float* __restrict__ x, const ushort* __restrict__ Wh,
    const ushort* __restrict__ Wl, float* __restrict__ outA,
    float* __restrict__ outB, int pixbase)
{
    int tid  = threadIdx.x;
    int lane = tid & 63;
    int wid  = __builtin_amdgcn_readfirstlane(tid >> 6);
    int lr = lane & 15, kg = lane >> 4;
    int pw = pixbase + wid * 32;              // wave's first pixel
    int b  = pw >> 14;                        // uniform per block
    int pr = pw & (HW_ - 1);

    const float* xb = x + ((size_t)b * DIM_ << 14) + pr + lr;

    f32x4 acc[MT][2];
#pragma unroll
    for (int mt = 0; mt < MT; ++mt)
#pragma unroll
        for (int nt = 0; nt < 2; ++nt) {
            f32x4 z = {0.f, 0.f, 0.f, 0.f};
            acc[mt][nt] = z;
        }

    for (int kc = 0; kc < 8; ++kc) {
        short8 bh[2], bl[2];
#pragma unroll
        for (int nt = 0; nt < 2; ++nt) {
            float xv[8];
#pragma unroll
            for (int j = 0; j < 8; ++j)
                xv[j] = xb[((size_t)(kc * 32 + kg * 8 + j) << 14) + nt * 16];
#pragma unroll
            for (int j = 0; j < 8; ++j) {
                ushort h = f2bf(xv[j]);
                bh[nt][j] = (short)h;
                bl[nt][j] = (short)f2bf(xv[j] - bf2f(h));
            }
        }
#pragma unroll
        for (int mt = 0; mt < MT; ++mt) {
            short8 ah = *(const short8*)(Wh + (((mt * 8 + kc) << 6) + lane) * 8);
            short8 al = *(const short8*)(Wl + (((mt * 8 + kc) << 6) + lane) * 8);
#pragma unroll
            for (int nt = 0; nt < 2; ++nt) {
                acc[mt][nt] = __builtin_amdgcn_mfma_f32_16x16x32_bf16(ah, bh[nt], acc[mt][nt], 0, 0, 0);
                acc[mt][nt] = __builtin_amdgcn_mfma_f32_16x16x32_bf16(ah, bl[nt], acc[mt][nt], 0, 0, 0);
                acc[mt][nt] = __builtin_amdgcn_mfma_f32_16x16x32_bf16(al, bh[nt], acc[mt][nt], 0, 0, 0);
            }
        }
    }

#pragma unroll
    for (int mt = 0; mt < MT; ++mt) {
#pragma unroll
        for (int nt = 0; nt < 2; ++nt) {
            f32x4 v = acc[mt][nt];
            if (mt < NORM_MT) {               // l2norm over the head's 16 rows
                float s = v.x * v.x + v.y * v.y + v.z * v.z + v.w * v.w;
                s += __shfl_xor(s, 16);       // lanes {lr, lr+16, lr+32, lr+48}
                s += __shfl_xor(s, 32);
                float inv = 1.f / fmaxf(sqrtf(s), 1e-12f);
                v.x *= inv; v.y *= inv; v.z *= inv; v.w *= inv;
            }
            int head = (mt < 4) ? mt : mt - 4;
            float* dst = ((mt < 4) ? outA : outB)
                + (((size_t)(b * HEADS_ + head) << 14) + pr + nt * 16 + lr) * HD_ + kg * 4;
            *(f32x4*)dst = v;
        }
    }
}

// bid < 512: Q-role (M=64, all heads normalized); else KV-role (M=128, K norm, V raw)
__global__ __launch_bounds__(256) void k_qkv(
    const float* __restrict__ q_in, const float* __restrict__ kv_in,
    const ushort* __restrict__ WfQh, const ushort* __restrict__ WfQl,
    const ushort* __restrict__ WfKVh, const ushort* __restrict__ WfKVl,
    float* __restrict__ qh, float* __restrict__ kh, float* __restrict__ vv)
{
    int bid = blockIdx.x;
    if (bid < 512) {
        proj_mfma<4, 4>(q_in, WfQh, WfQl, qh, qh, bid * 128);
    } else {
        proj_mfma<8, 4>(kv_in, WfKVh, WfKVl, kh, vv, (bid - 512) * 128);
    }
}

__device__ __forceinline__ int refl(int i, int n) {
    if (i < 0) i = -i;
    if (i >= n) i = 2 * n - 2 - i;
    return i;
}

// ---------------- sliding-window attention: one thread per (b,head,pixel) ----
__global__ __launch_bounds__(256) void k_attn(
    const float* __restrict__ qh, const float* __restrict__ kh,
    const float* __restrict__ vv, float* __restrict__ ao)
{
    int gid = blockIdx.x * blockDim.x + threadIdx.x;   // (b*4+h)*HW + p
    int p  = gid & (HW_ - 1);
    int bh = gid >> 14;
    int y = p >> 7, x = p & (W_ - 1);

    const float* qp = qh + ((size_t)bh * HW_ + p) * HD_;
    float4 q0 = *(const float4*)(qp + 0);
    float4 q1 = *(const float4*)(qp + 4);
    float4 q2 = *(const float4*)(qp + 8);
    float4 q3 = *(const float4*)(qp + 12);

    float logit[WS_ * WS_];
    int   nidx [WS_ * WS_];
#pragma unroll
    for (int i = 0; i < WS_; ++i) {
        int ry = refl(y + i - PAD_, H_);
#pragma unroll
        for (int j = 0; j < WS_; ++j) {
            int rx = refl(x + j - PAD_, W_);
            int np_ = ry * W_ + rx;
            nidx[i*WS_ + j] = np_;
            const float* kp = kh + ((size_t)bh * HW_ + np_) * HD_;
            float4 ka = *(const float4*)(kp + 0);
            float4 kb = *(const float4*)(kp + 4);
            float4 kc = *(const float4*)(kp + 8);
            float4 kd = *(const float4*)(kp + 12);
            float d = 0.f;
            d = fmaf(q0.x, ka.x, d); d = fmaf(q0.y, ka.y, d);
            d = fmaf(q0.z, ka.z, d); d = fmaf(q0.w, ka.w, d);
            d = fmaf(q1.x, kb.x, d); d = fmaf(q1.y, kb.y, d);
            d = fmaf(q1.z, kb.z, d); d = fmaf(q1.w, kb.w, d);
            d = fmaf(q2.x, kc.x, d); d = fmaf(q2.y, kc.y, d);
            d = fmaf(q2.z, kc.z, d); d = fmaf(q2.w, kc.w, d);
            d = fmaf(q3.x, kd.x, d); d = fmaf(q3.y, kd.y, d);
            d = fmaf(q3.z, kd.z, d); d = fmaf(q3.w, kd.w, d);
            logit[i*WS_ + j] = d;
        }
    }

    float m = logit[0];
#pragma unroll
    for (int w = 1; w < WS_*WS_; ++w) m = fmaxf(m, logit[w]);
    float s = 0.f;
#pragma unroll
    for (int w = 0; w < WS_*WS_; ++w) { float e = expf(logit[w] - m); logit[w] = e; s += e; }
    float invs = 1.f / s;

    float a[HD_];
#pragma unroll
    for (int d = 0; d < HD_; ++d) a[d] = 0.f;
#pragma unroll
    for (int w = 0; w < WS_*WS_; ++w) {
        float wt = logit[w] * invs;
        const float* vp = vv + ((size_t)bh * HW_ + nidx[w]) * HD_;
        float4 va = *(const float4*)(vp + 0);
        float4 vb = *(const float4*)(vp + 4);
        float4 vc = *(const float4*)(vp + 8);
        float4 vd = *(const float4*)(vp + 12);
        a[0]  = fmaf(wt, va.x, a[0]);  a[1]  = fmaf(wt, va.y, a[1]);
        a[2]  = fmaf(wt, va.z, a[2]);  a[3]  = fmaf(wt, va.w, a[3]);
        a[4]  = fmaf(wt, vb.x, a[4]);  a[5]  = fmaf(wt, vb.y, a[5]);
        a[6]  = fmaf(wt, vb.z, a[6]);  a[7]  = fmaf(wt, vb.w, a[7]);
        a[8]  = fmaf(wt, vc.x, a[8]);  a[9]  = fmaf(wt, vc.y, a[9]);
        a[10] = fmaf(wt, vc.z, a[10]); a[11] = fmaf(wt, vc.w, a[11]);
        a[12] = fmaf(wt, vd.x, a[12]); a[13] = fmaf(wt, vd.y, a[13]);
        a[14] = fmaf(wt, vd.z, a[14]); a[15] = fmaf(wt, vd.w, a[15]);
    }

    int b = bh >> 2, h = bh & 3;
    float* aop = ao + ((size_t)b * HW_ + p) * AD_ + h * HD_;
    *(float4*)(aop + 0)  = make_float4(a[0],  a[1],  a[2],  a[3]);
    *(float4*)(aop + 4)  = make_float4(a[4],  a[5],  a[6],  a[7]);
    *(float4*)(aop + 8)  = make_float4(a[8],  a[9],  a[10], a[11]);
    *(float4*)(aop + 12) = make_float4(a[12], a[13], a[14], a[15]);
}

// ---------------- output projection: out[b, oc, p] = sum_c WoT[c][oc] * ao[b,p,c]
__global__ __launch_bounds__(256) void k_oproj(
    const float* __restrict__ ao, const float* __restrict__ WoT,
    float* __restrict__ out)
{
    int lane = threadIdx.x & 63;
    int och  = __builtin_amdgcn_readfirstlane((int)(threadIdx.x >> 6)); // 0..3, SGPR
    int pix  = blockIdx.x * 64 + lane;                                  // 0..65535
    int b = pix >> 14;
    int p = pix & (HW_ - 1);
    const float* xp = ao + (size_t)pix * AD_;

    float acc[64];
#pragma unroll
    for (int o = 0; o < 64; ++o) acc[o] = 0.f;

    for (int c4 = 0; c4 < AD_ / 4; ++c4) {
        float4 xv = *(const float4*)(xp + c4 * 4);
#pragma unroll
        for (int cc = 0; cc < 4; ++cc) {
            float xs = (cc == 0) ? xv.x : (cc == 1) ? xv.y : (cc == 2) ? xv.z : xv.w;
            const float* wr = WoT + (size_t)(c4*4 + cc) * DIM_ + och * 64;  // uniform -> s_load
#pragma unroll
            for (int o = 0; o < 64; ++o) acc[o] = fmaf(wr[o], xs, acc[o]);
        }
    }

    float* op = out + (size_t)b * DIM_ * HW_ + (size_t)och * 64 * HW_ + p;
#pragma unroll
    for (int o = 0; o < 64; ++o) op[(size_t)o * HW_] = acc[o];
}

extern "C" void kernel_launch(void* const* d_in, const int* in_sizes, int n_in,
                              void* d_out, int out_size, void* d_ws, size_t ws_size,
                              hipStream_t stream) {
    const float* q_in  = (const float*)d_in[0];
    const float* kv_in = (const float*)d_in[1];
    const float* Wq    = (const float*)d_in[2];
    const float* Wk    = (const float*)d_in[3];
    const float* Wv    = (const float*)d_in[4];
    const float* Wo    = (const float*)d_in[5];
    float* out = (float*)d_out;

    float* wsf = (float*)d_ws;
    // frag arrays occupy the space formerly used by WqT/WkT/WvT (3*16384 floats)
    ushort* u    = (ushort*)wsf;
    ushort* WfQh  = u;            // 16384 shorts
    ushort* WfQl  = u + 16384;    // 16384
    ushort* WfKVh = u + 32768;    // 32768
    ushort* WfKVl = u + 65536;    // 32768  (ends at 98304 sh = 49152 floats)
    float* WoT = wsf + 49152;
    size_t tens = (size_t)B_ * HEADS_ * HW_ * HD_;   // 4,194,304 floats
    float* qh = wsf + 65536;
    float* kh = qh + tens;
    float* vv = kh + tens;
    float* ao = vv + tens;

    k_prep<<<dim3(192), dim3(256), 0, stream>>>(Wq, Wk, Wv, Wo,
                                                WfQh, WfQl, WfKVh, WfKVl, WoT);
    k_qkv<<<dim3(1024), dim3(256), 0, stream>>>(q_in, kv_in,
                                                WfQh, WfQl, WfKVh, WfKVl, qh, kh, vv);
    k_attn <<<dim3(1024), dim3(256), 0, stream>>>(qh, kh, vv, ao);
    k_oproj<<<dim3(1024), dim3(256), 0, stream>>>(ao, WoT, out);
}

// Round 6
// 161.937 us; speedup vs baseline: 1.4512x; 1.0395x over previous
//
#include <hip/hip_runtime.h>
#include <hip/hip_bf16.h>
#include <math.h>

#define B_ 4
#define DIM_ 256
#define H_ 128
#define W_ 128
#define HW_ (H_ * W_)
#define AD_ 64
#define HEADS_ 4
#define HD_ 16
#define WS_ 5
#define PAD_ 2

typedef __attribute__((ext_vector_type(8))) short short8;
typedef __attribute__((ext_vector_type(4))) float f32x4;

__device__ __forceinline__ ushort f2bf(float f) {
    unsigned u = __builtin_bit_cast(unsigned, f);
    unsigned r = u + 0x7FFFu + ((u >> 16) & 1u);
    return (ushort)(r >> 16);
}
__device__ __forceinline__ float bf2f(ushort h) {
    return __builtin_bit_cast(float, (unsigned)h << 16);
}

// ---------------- prep: WoT for oproj + fragment-ordered bf16 hi/lo weights --
// A-fragment layout for mfma_f32_16x16x32_bf16: lane l holds A[o=l&15][c] for
// 8 c's = kc*32 + (l>>4)*8 + j. The SAME (lane,j)->c map is used for the B
// gather in k_qkv, so the contraction is correct under any consistent k-perm.
__global__ __launch_bounds__(256) void k_prep(
    const float* __restrict__ Wq, const float* __restrict__ Wk,
    const float* __restrict__ Wv, const float* __restrict__ Wo,
    ushort* __restrict__ WfQh, ushort* __restrict__ WfQl,
    ushort* __restrict__ WfKVh, ushort* __restrict__ WfKVl,
    float* __restrict__ WoT)
{
    int i = blockIdx.x * 256 + threadIdx.x;          // 0 .. 49151
    if (i < AD_ * DIM_) {                            // WoT: (256,64) -> (64,256)
        int o2 = i / AD_, c2 = i % AD_;
        WoT[c2 * DIM_ + o2] = Wo[i];
    }
    if (i < 16384) {                                 // Q frags: 4mt*8kc*64l*8j
        int j = i & 7, l = (i >> 3) & 63, kc = (i >> 9) & 7, mt = i >> 12;
        int o = mt * 16 + (l & 15);
        int c = kc * 32 + ((l >> 4) & 3) * 8 + j;
        float wv = Wq[o * DIM_ + c];
        ushort h = f2bf(wv);
        WfQh[i] = h;
        WfQl[i] = f2bf(wv - bf2f(h));
    } else if (i < 49152) {                          // KV frags: 8mt (K:0-3, V:4-7)
        int ii = i - 16384;
        int j = ii & 7, l = (ii >> 3) & 63, kc = (ii >> 9) & 7, mt = ii >> 12;
        const float* Ws = (mt < 4) ? Wk : Wv;
        int o = (mt & 3) * 16 + (l & 15);
        int c = kc * 32 + ((l >> 4) & 3) * 8 + j;
        float wv = Ws[o * DIM_ + c];
        ushort h = f2bf(wv);
        WfKVh[ii] = h;
        WfKVl[ii] = f2bf(wv - bf2f(h));
    }
}

// ---------------- QKV projection v6: bf16x3 MFMA, 3 equal roles --------------
// Wave tile: M = 64 outputs x N = 32 pixels, K = 256 in 8 chunks of 32.
// role = bid%3 (0=Q 1=K 2=V) -> uniform work per block (no MT=8 tail),
// K/V blocks for the same pixels temporally adjacent -> kv_in L2/L3-hot.
// grid 1536 = 6 blocks/CU = 24 waves/CU (vs R5's 4 blocks + 2x imbalance).
// acc += Ahi*Bhi + Ahi*Blo + Alo*Bhi  (f32 accumulate, err ~1e-5 rel).
template<bool NORM>
__device__ __forceinline__ void proj_mfma4(
    const float* __restrict__ x, const ushort* __restrict__ Wh,
    const ushort* __restrict__ Wl, float* __restrict__ outp, int pixbase)
{
    int tid  = threadIdx.x;
    int lane = tid & 63;
    int wid  = __builtin_amdgcn_readfirstlane(tid >> 6);
    int lr = lane & 15, kg = lane >> 4;
    int pw = pixbase + wid * 32;              // wave's first pixel
    int b  = pw >> 14;                        // uniform per block
    int pr = pw & (HW_ - 1);

    const float* xb = x + ((size_t)b * DIM_ << 14) + pr + lr;

    f32x4 acc[4][2];
#pragma unroll
    for (int mt = 0; mt < 4; ++mt)
#pragma unroll
        for (int nt = 0; nt < 2; ++nt) {
            f32x4 z = {0.f, 0.f, 0.f, 0.f};
            acc[mt][nt] = z;
        }

    for (int kc = 0; kc < 8; ++kc) {
        short8 bh[2], bl[2];
#pragma unroll
        for (int nt = 0; nt < 2; ++nt) {
            float xv[8];
#pragma unroll
            for (int j = 0; j < 8; ++j)
                xv[j] = xb[((size_t)(kc * 32 + kg * 8 + j) << 14) + nt * 16];
#pragma unroll
            for (int j = 0; j < 8; ++j) {
                ushort h = f2bf(xv[j]);
                bh[nt][j] = (short)h;
                bl[nt][j] = (short)f2bf(xv[j] - bf2f(h));
            }
        }
#pragma unroll
        for (int mt = 0; mt < 4; ++mt) {
            short8 ah = *(const short8*)(Wh + (((mt * 8 + kc) << 6) + lane) * 8);
            short8 al = *(const short8*)(Wl + (((mt * 8 + kc) << 6) + lane) * 8);
#pragma unroll
            for (int nt = 0; nt < 2; ++nt) {
                acc[mt][nt] = __builtin_amdgcn_mfma_f32_16x16x32_bf16(ah, bh[nt], acc[mt][nt], 0, 0, 0);
                acc[mt][nt] = __builtin_amdgcn_mfma_f32_16x16x32_bf16(ah, bl[nt], acc[mt][nt], 0, 0, 0);
                acc[mt][nt] = __builtin_amdgcn_mfma_f32_16x16x32_bf16(al, bh[nt], acc[mt][nt], 0, 0, 0);
            }
        }
    }

#pragma unroll
    for (int mt = 0; mt < 4; ++mt) {
#pragma unroll
        for (int nt = 0; nt < 2; ++nt) {
            f32x4 v = acc[mt][nt];
            if (NORM) {                       // l2norm over the head's 16 rows
                float s = v.x * v.x + v.y * v.y + v.z * v.z + v.w * v.w;
                s += __shfl_xor(s, 16);       // lanes {lr, lr+16, lr+32, lr+48}
                s += __shfl_xor(s, 32);
                float inv = 1.f / fmaxf(sqrtf(s), 1e-12f);
                v.x *= inv; v.y *= inv; v.z *= inv; v.w *= inv;
            }
            float* dst = outp
                + (((size_t)(b * HEADS_ + mt) << 14) + pr + nt * 16 + lr) * HD_ + kg * 4;
            *(f32x4*)dst = v;
        }
    }
}

// role = bid%3: 0=Q (norm), 1=K (norm), 2=V (raw). g = bid/3 -> 128-pixel group.
__global__ __launch_bounds__(256) void k_qkv(
    const float* __restrict__ q_in, const float* __restrict__ kv_in,
    const ushort* __restrict__ WfQh, const ushort* __restrict__ WfQl,
    const ushort* __restrict__ WfKVh, const ushort* __restrict__ WfKVl,
    float* __restrict__ qh, float* __restrict__ kh, float* __restrict__ vv)
{
    int bid  = blockIdx.x;
    int g    = bid / 3;
    int role = bid - g * 3;
    if (role == 0)      proj_mfma4<true >(q_in,  WfQh,          WfQl,          qh, g * 128);
    else if (role == 1) proj_mfma4<true >(kv_in, WfKVh,         WfKVl,         kh, g * 128);
    else                proj_mfma4<false>(kv_in, WfKVh + 16384, WfKVl + 16384, vv, g * 128);
}

__device__ __forceinline__ int refl(int i, int n) {
    if (i < 0) i = -i;
    if (i >= n) i = 2 * n - 2 - i;
    return i;
}

// ---------------- sliding-window attention: one thread per (b,head,pixel) ----
__global__ __launch_bounds__(256) void k_attn(
    const float* __restrict__ qh, const float* __restrict__ kh,
    const float* __restrict__ vv, float* __restrict__ ao)
{
    int gid = blockIdx.x * blockDim.x + threadIdx.x;   // (b*4+h)*HW + p
    int p  = gid & (HW_ - 1);
    int bh = gid >> 14;
    int y = p >> 7, x = p & (W_ - 1);

    const float* qp = qh + ((size_t)bh * HW_ + p) * HD_;
    float4 q0 = *(const float4*)(qp + 0);
    float4 q1 = *(const float4*)(qp + 4);
    float4 q2 = *(const float4*)(qp + 8);
    float4 q3 = *(const float4*)(qp + 12);

    float logit[WS_ * WS_];
    int   nidx [WS_ * WS_];
#pragma unroll
    for (int i = 0; i < WS_; ++i) {
        int ry = refl(y + i - PAD_, H_);
#pragma unroll
        for (int j = 0; j < WS_; ++j) {
            int rx = refl(x + j - PAD_, W_);
            int np_ = ry * W_ + rx;
            nidx[i*WS_ + j] = np_;
            const float* kp = kh + ((size_t)bh * HW_ + np_) * HD_;
            float4 ka = *(const float4*)(kp + 0);
            float4 kb = *(const float4*)(kp + 4);
            float4 kc = *(const float4*)(kp + 8);
            float4 kd = *(const float4*)(kp + 12);
            float d = 0.f;
            d = fmaf(q0.x, ka.x, d); d = fmaf(q0.y, ka.y, d);
            d = fmaf(q0.z, ka.z, d); d = fmaf(q0.w, ka.w, d);
            d = fmaf(q1.x, kb.x, d); d = fmaf(q1.y, kb.y, d);
            d = fmaf(q1.z, kb.z, d); d = fmaf(q1.w, kb.w, d);
            d = fmaf(q2.x, kc.x, d); d = fmaf(q2.y, kc.y, d);
            d = fmaf(q2.z, kc.z, d); d = fmaf(q2.w, kc.w, d);
            d = fmaf(q3.x, kd.x, d); d = fmaf(q3.y, kd.y, d);
            d = fmaf(q3.z, kd.z, d); d = fmaf(q3.w, kd.w, d);
            logit[i*WS_ + j] = d;
        }
    }

    float m = logit[0];
#pragma unroll
    for (int w = 1; w < WS_*WS_; ++w) m = fmaxf(m, logit[w]);
    float s = 0.f;
#pragma unroll
    for (int w = 0; w < WS_*WS_; ++w) { float e = expf(logit[w] - m); logit[w] = e; s += e; }
    float invs = 1.f / s;

    float a[HD_];
#pragma unroll
    for (int d = 0; d < HD_; ++d) a[d] = 0.f;
#pragma unroll
    for (int w = 0; w < WS_*WS_; ++w) {
        float wt = logit[w] * invs;
        const float* vp = vv + ((size_t)bh * HW_ + nidx[w]) * HD_;
        float4 va = *(const float4*)(vp + 0);
        float4 vb = *(const float4*)(vp + 4);
        float4 vc = *(const float4*)(vp + 8);
        float4 vd = *(const float4*)(vp + 12);
        a[0]  = fmaf(wt, va.x, a[0]);  a[1]  = fmaf(wt, va.y, a[1]);
        a[2]  = fmaf(wt, va.z, a[2]);  a[3]  = fmaf(wt, va.w, a[3]);
        a[4]  = fmaf(wt, vb.x, a[4]);  a[5]  = fmaf(wt, vb.y, a[5]);
        a[6]  = fmaf(wt, vb.z, a[6]);  a[7]  = fmaf(wt, vb.w, a[7]);
        a[8]  = fmaf(wt, vc.x, a[8]);  a[9]  = fmaf(wt, vc.y, a[9]);
        a[10] = fmaf(wt, vc.z, a[10]); a[11] = fmaf(wt, vc.w, a[11]);
        a[12] = fmaf(wt, vd.x, a[12]); a[13] = fmaf(wt, vd.y, a[13]);
        a[14] = fmaf(wt, vd.z, a[14]); a[15] = fmaf(wt, vd.w, a[15]);
    }

    int b = bh >> 2, h = bh & 3;
    float* aop = ao + ((size_t)b * HW_ + p) * AD_ + h * HD_;
    *(float4*)(aop + 0)  = make_float4(a[0],  a[1],  a[2],  a[3]);
    *(float4*)(aop + 4)  = make_float4(a[4],  a[5],  a[6],  a[7]);
    *(float4*)(aop + 8)  = make_float4(a[8],  a[9],  a[10], a[11]);
    *(float4*)(aop + 12) = make_float4(a[12], a[13], a[14], a[15]);
}

// ---------------- output projection: out[b, oc, p] = sum_c WoT[c][oc] * ao[b,p,c]
__global__ __launch_bounds__(256) void k_oproj(
    const float* __restrict__ ao, const float* __restrict__ WoT,
    float* __restrict__ out)
{
    int lane = threadIdx.x & 63;
    int och  = __builtin_amdgcn_readfirstlane((int)(threadIdx.x >> 6)); // 0..3, SGPR
    int pix  = blockIdx.x * 64 + lane;                                  // 0..65535
    int b = pix >> 14;
    int p = pix & (HW_ - 1);
    const float* xp = ao + (size_t)pix * AD_;

    float acc[64];
#pragma unroll
    for (int o = 0; o < 64; ++o) acc[o] = 0.f;

    for (int c4 = 0; c4 < AD_ / 4; ++c4) {
        float4 xv = *(const float4*)(xp + c4 * 4);
#pragma unroll
        for (int cc = 0; cc < 4; ++cc) {
            float xs = (cc == 0) ? xv.x : (cc == 1) ? xv.y : (cc == 2) ? xv.z : xv.w;
            const float* wr = WoT + (size_t)(c4*4 + cc) * DIM_ + och * 64;  // uniform -> s_load
#pragma unroll
            for (int o = 0; o < 64; ++o) acc[o] = fmaf(wr[o], xs, acc[o]);
        }
    }

    float* op = out + (size_t)b * DIM_ * HW_ + (size_t)och * 64 * HW_ + p;
#pragma unroll
    for (int o = 0; o < 64; ++o) op[(size_t)o * HW_] = acc[o];
}

extern "C" void kernel_launch(void* const* d_in, const int* in_sizes, int n_in,
                              void* d_out, int out_size, void* d_ws, size_t ws_size,
                              hipStream_t stream) {
    const float* q_in  = (const float*)d_in[0];
    const float* kv_in = (const float*)d_in[1];
    const float* Wq    = (const float*)d_in[2];
    const float* Wk    = (const float*)d_in[3];
    const float* Wv    = (const float*)d_in[4];
    const float* Wo    = (const float*)d_in[5];
    float* out = (float*)d_out;

    float* wsf = (float*)d_ws;
    ushort* u    = (ushort*)wsf;
    ushort* WfQh  = u;            // 16384 shorts
    ushort* WfQl  = u + 16384;    // 16384
    ushort* WfKVh = u + 32768;    // 32768 (K: first 16384, V: last 16384)
    ushort* WfKVl = u + 65536;    // 32768  (ends at 98304 sh = 49152 floats)
    float* WoT = wsf + 49152;
    size_t tens = (size_t)B_ * HEADS_ * HW_ * HD_;   // 4,194,304 floats
    float* qh = wsf + 65536;
    float* kh = qh + tens;
    float* vv = kh + tens;
    float* ao = vv + tens;

    k_prep<<<dim3(192), dim3(256), 0, stream>>>(Wq, Wk, Wv, Wo,
                                                WfQh, WfQl, WfKVh, WfKVl, WoT);
    k_qkv<<<dim3(1536), dim3(256), 0, stream>>>(q_in, kv_in,
                                                WfQh, WfQl, WfKVh, WfKVl, qh, kh, vv);
    k_attn <<<dim3(1024), dim3(256), 0, stream>>>(qh, kh, vv, ao);
    k_oproj<<<dim3(1024), dim3(256), 0, stream>>>(ao, WoT, out);
}

// Round 7
// 135.195 us; speedup vs baseline: 1.7383x; 1.1978x over previous
//
#include <hip/hip_runtime.h>
#include <hip/hip_bf16.h>
#include <math.h>

#define B_ 4
#define DIM_ 256
#define H_ 128
#define W_ 128
#define HW_ (H_ * W_)
#define AD_ 64
#define HEADS_ 4
#define HD_ 16
#define WS_ 5
#define PAD_ 2

typedef __attribute__((ext_vector_type(8))) short short8;
typedef __attribute__((ext_vector_type(4))) float f32x4;

__device__ __forceinline__ ushort f2bf(float f) {
    unsigned u = __builtin_bit_cast(unsigned, f);
    unsigned r = u + 0x7FFFu + ((u >> 16) & 1u);
    return (ushort)(r >> 16);
}
__device__ __forceinline__ float bf2f(ushort h) {
    return __builtin_bit_cast(float, (unsigned)h << 16);
}

// ---------------- prep: WoT for oproj + fragment-ordered bf16 hi/lo weights --
// A-fragment layout for mfma_f32_16x16x32_bf16: lane l holds A[o=l&15][c] for
// 8 c's = kc*32 + (l>>4)*8 + j. The SAME (lane,j)->c map is used for the B
// gather in k_qkv, so the contraction is correct under any consistent k-perm.
__global__ __launch_bounds__(256) void k_prep(
    const float* __restrict__ Wq, const float* __restrict__ Wk,
    const float* __restrict__ Wv, const float* __restrict__ Wo,
    ushort* __restrict__ WfQh, ushort* __restrict__ WfQl,
    ushort* __restrict__ WfKVh, ushort* __restrict__ WfKVl,
    float* __restrict__ WoT)
{
    int i = blockIdx.x * 256 + threadIdx.x;          // 0 .. 49151
    if (i < AD_ * DIM_) {                            // WoT: (256,64) -> (64,256)
        int o2 = i / AD_, c2 = i % AD_;
        WoT[c2 * DIM_ + o2] = Wo[i];
    }
    if (i < 16384) {                                 // Q frags: 4mt*8kc*64l*8j
        int j = i & 7, l = (i >> 3) & 63, kc = (i >> 9) & 7, mt = i >> 12;
        int o = mt * 16 + (l & 15);
        int c = kc * 32 + ((l >> 4) & 3) * 8 + j;
        float wv = Wq[o * DIM_ + c];
        ushort h = f2bf(wv);
        WfQh[i] = h;
        WfQl[i] = f2bf(wv - bf2f(h));
    } else if (i < 49152) {                          // KV frags: 8mt (K:0-3, V:4-7)
        int ii = i - 16384;
        int j = ii & 7, l = (ii >> 3) & 63, kc = (ii >> 9) & 7, mt = ii >> 12;
        const float* Ws = (mt < 4) ? Wk : Wv;
        int o = (mt & 3) * 16 + (l & 15);
        int c = kc * 32 + ((l >> 4) & 3) * 8 + j;
        float wv = Ws[o * DIM_ + c];
        ushort h = f2bf(wv);
        WfKVh[ii] = h;
        WfKVl[ii] = f2bf(wv - bf2f(h));
    }
}

// ---------------- QKV projection v6: bf16x3 MFMA, 3 equal roles --------------
template<bool NORM>
__device__ __forceinline__ void proj_mfma4(
    const float* __restrict__ x, const ushort* __restrict__ Wh,
    const ushort* __restrict__ Wl, float* __restrict__ outp, int pixbase)
{
    int tid  = threadIdx.x;
    int lane = tid & 63;
    int wid  = __builtin_amdgcn_readfirstlane(tid >> 6);
    int lr = lane & 15, kg = lane >> 4;
    int pw = pixbase + wid * 32;              // wave's first pixel
    int b  = pw >> 14;                        // uniform per block
    int pr = pw & (HW_ - 1);

    const float* xb = x + ((size_t)b * DIM_ << 14) + pr + lr;

    f32x4 acc[4][2];
#pragma unroll
    for (int mt = 0; mt < 4; ++mt)
#pragma unroll
        for (int nt = 0; nt < 2; ++nt) {
            f32x4 z = {0.f, 0.f, 0.f, 0.f};
            acc[mt][nt] = z;
        }

    for (int kc = 0; kc < 8; ++kc) {
        short8 bh[2], bl[2];
#pragma unroll
        for (int nt = 0; nt < 2; ++nt) {
            float xv[8];
#pragma unroll
            for (int j = 0; j < 8; ++j)
                xv[j] = xb[((size_t)(kc * 32 + kg * 8 + j) << 14) + nt * 16];
#pragma unroll
            for (int j = 0; j < 8; ++j) {
                ushort h = f2bf(xv[j]);
                bh[nt][j] = (short)h;
                bl[nt][j] = (short)f2bf(xv[j] - bf2f(h));
            }
        }
#pragma unroll
        for (int mt = 0; mt < 4; ++mt) {
            short8 ah = *(const short8*)(Wh + (((mt * 8 + kc) << 6) + lane) * 8);
            short8 al = *(const short8*)(Wl + (((mt * 8 + kc) << 6) + lane) * 8);
#pragma unroll
            for (int nt = 0; nt < 2; ++nt) {
                acc[mt][nt] = __builtin_amdgcn_mfma_f32_16x16x32_bf16(ah, bh[nt], acc[mt][nt], 0, 0, 0);
                acc[mt][nt] = __builtin_amdgcn_mfma_f32_16x16x32_bf16(ah, bl[nt], acc[mt][nt], 0, 0, 0);
                acc[mt][nt] = __builtin_amdgcn_mfma_f32_16x16x32_bf16(al, bh[nt], acc[mt][nt], 0, 0, 0);
            }
        }
    }

#pragma unroll
    for (int mt = 0; mt < 4; ++mt) {
#pragma unroll
        for (int nt = 0; nt < 2; ++nt) {
            f32x4 v = acc[mt][nt];
            if (NORM) {                       // l2norm over the head's 16 rows
                float s = v.x * v.x + v.y * v.y + v.z * v.z + v.w * v.w;
                s += __shfl_xor(s, 16);       // lanes {lr, lr+16, lr+32, lr+48}
                s += __shfl_xor(s, 32);
                float inv = 1.f / fmaxf(sqrtf(s), 1e-12f);
                v.x *= inv; v.y *= inv; v.z *= inv; v.w *= inv;
            }
            float* dst = outp
                + (((size_t)(b * HEADS_ + mt) << 14) + pr + nt * 16 + lr) * HD_ + kg * 4;
            *(f32x4*)dst = v;
        }
    }
}

// role = bid%3: 0=Q (norm), 1=K (norm), 2=V (raw). g = bid/3 -> 128-pixel group.
__global__ __launch_bounds__(256) void k_qkv(
    const float* __restrict__ q_in, const float* __restrict__ kv_in,
    const ushort* __restrict__ WfQh, const ushort* __restrict__ WfQl,
    const ushort* __restrict__ WfKVh, const ushort* __restrict__ WfKVl,
    float* __restrict__ qh, float* __restrict__ kh, float* __restrict__ vv)
{
    int bid  = blockIdx.x;
    int g    = bid / 3;
    int role = bid - g * 3;
    if (role == 0)      proj_mfma4<true >(q_in,  WfQh,          WfQl,          qh, g * 128);
    else if (role == 1) proj_mfma4<true >(kv_in, WfKVh,         WfKVl,         kh, g * 128);
    else                proj_mfma4<false>(kv_in, WfKVh + 16384, WfKVl + 16384, vv, g * 128);
}

__device__ __forceinline__ int refl(int i, int n) {
    if (i < 0) i = -i;
    if (i >= n) i = 2 * n - 2 - i;
    return i;
}

// ---------------- sliding-window attention v7: split-d pair + XCD swizzle ----
// 2 lanes per (bh,pixel): lane (pl,t) handles dims [t*8, t*8+8). Logit =
// partial dot + shfl_xor(32) butterfly; softmax redundant per lane; PV
// accumulates 8 dims. Halves per-thread loads, doubles wave supply (2048
// blocks = 32 waves/CU). XCD swizzle: each XCD owns 2 contiguous (b,h)
// planes (K+V = 4 MB ~ its L2) so the 5x vertical row-reuse hits L2.
__global__ __launch_bounds__(256) void k_attn(
    const float* __restrict__ qh, const float* __restrict__ kh,
    const float* __restrict__ vv, float* __restrict__ ao)
{
    int bid = blockIdx.x;
    int swz = (bid & 7) * 256 + (bid >> 3);          // bijective on 2048
    int tid = threadIdx.x;
    int lane = tid & 63;
    int wv  = tid >> 6;                              // 0..3
    int t   = lane >> 5;                             // d-half: 0 or 1
    int pl  = lane & 31;

    int pix = swz * 128 + wv * 32 + pl;              // (bh*HW + p), 0..262143
    int p  = pix & (HW_ - 1);
    int bh = pix >> 14;
    int y = p >> 7, x = p & (W_ - 1);
    int to = t * 8;

    const float* qp = qh + ((size_t)bh * HW_ + p) * HD_ + to;
    float4 qa = *(const float4*)(qp + 0);
    float4 qb = *(const float4*)(qp + 4);

    float logit[WS_ * WS_];
    int   nidx [WS_ * WS_];
#pragma unroll
    for (int i = 0; i < WS_; ++i) {
        int ry = refl(y + i - PAD_, H_);
#pragma unroll
        for (int j = 0; j < WS_; ++j) {
            int rx = refl(x + j - PAD_, W_);
            int np_ = ry * W_ + rx;
            nidx[i*WS_ + j] = np_;
            const float* kp = kh + ((size_t)bh * HW_ + np_) * HD_ + to;
            float4 ka = *(const float4*)(kp + 0);
            float4 kb = *(const float4*)(kp + 4);
            float d = 0.f;
            d = fmaf(qa.x, ka.x, d); d = fmaf(qa.y, ka.y, d);
            d = fmaf(qa.z, ka.z, d); d = fmaf(qa.w, ka.w, d);
            d = fmaf(qb.x, kb.x, d); d = fmaf(qb.y, kb.y, d);
            d = fmaf(qb.z, kb.z, d); d = fmaf(qb.w, kb.w, d);
            logit[i*WS_ + j] = d + __shfl_xor(d, 32);   // combine d-halves
        }
    }

    float m = logit[0];
#pragma unroll
    for (int w = 1; w < WS_*WS_; ++w) m = fmaxf(m, logit[w]);
    float s = 0.f;
#pragma unroll
    for (int w = 0; w < WS_*WS_; ++w) { float e = expf(logit[w] - m); logit[w] = e; s += e; }
    float invs = 1.f / s;

    float a[8];
#pragma unroll
    for (int d = 0; d < 8; ++d) a[d] = 0.f;
#pragma unroll
    for (int w = 0; w < WS_*WS_; ++w) {
        float wt = logit[w] * invs;
        const float* vp = vv + ((size_t)bh * HW_ + nidx[w]) * HD_ + to;
        float4 va = *(const float4*)(vp + 0);
        float4 vb = *(const float4*)(vp + 4);
        a[0] = fmaf(wt, va.x, a[0]); a[1] = fmaf(wt, va.y, a[1]);
        a[2] = fmaf(wt, va.z, a[2]); a[3] = fmaf(wt, va.w, a[3]);
        a[4] = fmaf(wt, vb.x, a[4]); a[5] = fmaf(wt, vb.y, a[5]);
        a[6] = fmaf(wt, vb.z, a[6]); a[7] = fmaf(wt, vb.w, a[7]);
    }

    int b = bh >> 2, h = bh & 3;
    float* aop = ao + ((size_t)b * HW_ + p) * AD_ + h * HD_ + to;
    *(float4*)(aop + 0) = make_float4(a[0], a[1], a[2], a[3]);
    *(float4*)(aop + 4) = make_float4(a[4], a[5], a[6], a[7]);
}

// ---------------- output projection: out[b, oc, p] = sum_c WoT[c][oc] * ao[b,p,c]
__global__ __launch_bounds__(256) void k_oproj(
    const float* __restrict__ ao, const float* __restrict__ WoT,
    float* __restrict__ out)
{
    int lane = threadIdx.x & 63;
    int och  = __builtin_amdgcn_readfirstlane((int)(threadIdx.x >> 6)); // 0..3, SGPR
    int pix  = blockIdx.x * 64 + lane;                                  // 0..65535
    int b = pix >> 14;
    int p = pix & (HW_ - 1);
    const float* xp = ao + (size_t)pix * AD_;

    float acc[64];
#pragma unroll
    for (int o = 0; o < 64; ++o) acc[o] = 0.f;

    for (int c4 = 0; c4 < AD_ / 4; ++c4) {
        float4 xv = *(const float4*)(xp + c4 * 4);
#pragma unroll
        for (int cc = 0; cc < 4; ++cc) {
            float xs = (cc == 0) ? xv.x : (cc == 1) ? xv.y : (cc == 2) ? xv.z : xv.w;
            const float* wr = WoT + (size_t)(c4*4 + cc) * DIM_ + och * 64;  // uniform -> s_load
#pragma unroll
            for (int o = 0; o < 64; ++o) acc[o] = fmaf(wr[o], xs, acc[o]);
        }
    }

    float* op = out + (size_t)b * DIM_ * HW_ + (size_t)och * 64 * HW_ + p;
#pragma unroll
    for (int o = 0; o < 64; ++o) op[(size_t)o * HW_] = acc[o];
}

extern "C" void kernel_launch(void* const* d_in, const int* in_sizes, int n_in,
                              void* d_out, int out_size, void* d_ws, size_t ws_size,
                              hipStream_t stream) {
    const float* q_in  = (const float*)d_in[0];
    const float* kv_in = (const float*)d_in[1];
    const float* Wq    = (const float*)d_in[2];
    const float* Wk    = (const float*)d_in[3];
    const float* Wv    = (const float*)d_in[4];
    const float* Wo    = (const float*)d_in[5];
    float* out = (float*)d_out;

    float* wsf = (float*)d_ws;
    ushort* u    = (ushort*)wsf;
    ushort* WfQh  = u;            // 16384 shorts
    ushort* WfQl  = u + 16384;    // 16384
    ushort* WfKVh = u + 32768;    // 32768 (K: first 16384, V: last 16384)
    ushort* WfKVl = u + 65536;    // 32768  (ends at 98304 sh = 49152 floats)
    float* WoT = wsf + 49152;
    size_t tens = (size_t)B_ * HEADS_ * HW_ * HD_;   // 4,194,304 floats
    float* qh = wsf + 65536;
    float* kh = qh + tens;
    float* vv = kh + tens;
    float* ao = vv + tens;

    k_prep<<<dim3(192), dim3(256), 0, stream>>>(Wq, Wk, Wv, Wo,
                                                WfQh, WfQl, WfKVh, WfKVl, WoT);
    k_qkv<<<dim3(1536), dim3(256), 0, stream>>>(q_in, kv_in,
                                                WfQh, WfQl, WfKVh, WfKVl, qh, kh, vv);
    k_attn <<<dim3(2048), dim3(256), 0, stream>>>(qh, kh, vv, ao);
    k_oproj<<<dim3(1024), dim3(256), 0, stream>>>(ao, WoT, out);
}

// Round 8
// 133.239 us; speedup vs baseline: 1.7638x; 1.0147x over previous
//
#include <hip/hip_runtime.h>
#include <hip/hip_bf16.h>
#include <math.h>

#define B_ 4
#define DIM_ 256
#define H_ 128
#define W_ 128
#define HW_ (H_ * W_)
#define AD_ 64
#define HEADS_ 4
#define HD_ 16
#define WS_ 5
#define PAD_ 2

typedef __attribute__((ext_vector_type(8))) short short8;
typedef __attribute__((ext_vector_type(4))) float f32x4;

__device__ __forceinline__ ushort f2bf(float f) {
    unsigned u = __builtin_bit_cast(unsigned, f);
    unsigned r = u + 0x7FFFu + ((u >> 16) & 1u);
    return (ushort)(r >> 16);
}
__device__ __forceinline__ float bf2f(ushort h) {
    return __builtin_bit_cast(float, (unsigned)h << 16);
}

// ---------------- prep: WoT for oproj + fragment-ordered bf16 hi/lo weights --
// A-fragment layout for mfma_f32_16x16x32_bf16: lane l holds A[o=l&15][c] for
// 8 c's = kc*32 + (l>>4)*8 + j. The SAME (lane,j)->c map is used for the B
// gather in k_qkv, so the contraction is correct under any consistent k-perm.
__global__ __launch_bounds__(256) void k_prep(
    const float* __restrict__ Wq, const float* __restrict__ Wk,
    const float* __restrict__ Wv, const float* __restrict__ Wo,
    ushort* __restrict__ WfQh, ushort* __restrict__ WfQl,
    ushort* __restrict__ WfKVh, ushort* __restrict__ WfKVl,
    float* __restrict__ WoT)
{
    int i = blockIdx.x * 256 + threadIdx.x;          // 0 .. 49151
    if (i < AD_ * DIM_) {                            // WoT: (256,64) -> (64,256)
        int o2 = i / AD_, c2 = i % AD_;
        WoT[c2 * DIM_ + o2] = Wo[i];
    }
    if (i < 16384) {                                 // Q frags: 4mt*8kc*64l*8j
        int j = i & 7, l = (i >> 3) & 63, kc = (i >> 9) & 7, mt = i >> 12;
        int o = mt * 16 + (l & 15);
        int c = kc * 32 + ((l >> 4) & 3) * 8 + j;
        float wv = Wq[o * DIM_ + c];
        ushort h = f2bf(wv);
        WfQh[i] = h;
        WfQl[i] = f2bf(wv - bf2f(h));
    } else if (i < 49152) {                          // KV frags: 8mt (K:0-3, V:4-7)
        int ii = i - 16384;
        int j = ii & 7, l = (ii >> 3) & 63, kc = (ii >> 9) & 7, mt = ii >> 12;
        const float* Ws = (mt < 4) ? Wk : Wv;
        int o = (mt & 3) * 16 + (l & 15);
        int c = kc * 32 + ((l >> 4) & 3) * 8 + j;
        float wv = Ws[o * DIM_ + c];
        ushort h = f2bf(wv);
        WfKVh[ii] = h;
        WfKVl[ii] = f2bf(wv - bf2f(h));
    }
}

// ---------------- QKV projection v8: 16 px/wave + kc-prefetch ----------------
// Wave tile: M = 64 outputs x N = 16 pixels (one MFMA column tile), K = 256 in
// 8 chunks of 32. Halving px/wave doubles wave count: 12288 waves = 48/CU
// demand -> saturates the 32-wave/CU cap (R7 measured only ~12 resident).
// Explicit next-kc xv prefetch under full unroll deepens MLP: chunk kc+1's 8
// loads issue before chunk kc's MFMAs. MFMA sequence per output unchanged ->
// bitwise-identical results to v6/v7.
// acc += Ahi*Bhi + Ahi*Blo + Alo*Bhi  (f32 accumulate, err ~1e-5 rel).
template<bool NORM>
__device__ __forceinline__ void proj_mfma16(
    const float* __restrict__ x, const ushort* __restrict__ Wh,
    const ushort* __restrict__ Wl, float* __restrict__ outp, int pixbase)
{
    int tid  = threadIdx.x;
    int lane = tid & 63;
    int wid  = __builtin_amdgcn_readfirstlane(tid >> 6);
    int lr = lane & 15, kg = lane >> 4;
    int pw = pixbase + wid * 16;              // wave's 16 pixels
    int b  = pw >> 14;                        // uniform per block (64 | 16384)
    int pr = pw & (HW_ - 1);

    const float* xb = x + ((size_t)b * DIM_ << 14) + pr + lr;

    f32x4 acc[4];
#pragma unroll
    for (int mt = 0; mt < 4; ++mt) { f32x4 z = {0.f,0.f,0.f,0.f}; acc[mt] = z; }

    float xv[8];
#pragma unroll
    for (int j = 0; j < 8; ++j)               // preload kc=0
        xv[j] = xb[(size_t)(kg * 8 + j) << 14];

#pragma unroll
    for (int kc = 0; kc < 8; ++kc) {
        float xn[8];
        if (kc < 7) {                         // prefetch next chunk early
#pragma unroll
            for (int j = 0; j < 8; ++j)
                xn[j] = xb[(size_t)((kc + 1) * 32 + kg * 8 + j) << 14];
        }
        short8 bh, bl;
#pragma unroll
        for (int j = 0; j < 8; ++j) {
            ushort h = f2bf(xv[j]);
            bh[j] = (short)h;
            bl[j] = (short)f2bf(xv[j] - bf2f(h));
        }
#pragma unroll
        for (int mt = 0; mt < 4; ++mt) {
            short8 ah = *(const short8*)(Wh + (((mt * 8 + kc) << 6) + lane) * 8);
            short8 al = *(const short8*)(Wl + (((mt * 8 + kc) << 6) + lane) * 8);
            acc[mt] = __builtin_amdgcn_mfma_f32_16x16x32_bf16(ah, bh, acc[mt], 0, 0, 0);
            acc[mt] = __builtin_amdgcn_mfma_f32_16x16x32_bf16(ah, bl, acc[mt], 0, 0, 0);
            acc[mt] = __builtin_amdgcn_mfma_f32_16x16x32_bf16(al, bh, acc[mt], 0, 0, 0);
        }
        if (kc < 7) {
#pragma unroll
            for (int j = 0; j < 8; ++j) xv[j] = xn[j];
        }
    }

#pragma unroll
    for (int mt = 0; mt < 4; ++mt) {
        f32x4 v = acc[mt];
        if (NORM) {                           // l2norm over the head's 16 rows
            float s = v.x * v.x + v.y * v.y + v.z * v.z + v.w * v.w;
            s += __shfl_xor(s, 16);           // lanes {lr, lr+16, lr+32, lr+48}
            s += __shfl_xor(s, 32);
            float inv = 1.f / fmaxf(sqrtf(s), 1e-12f);
            v.x *= inv; v.y *= inv; v.z *= inv; v.w *= inv;
        }
        float* dst = outp
            + (((size_t)(b * HEADS_ + mt) << 14) + pr + lr) * HD_ + kg * 4;
        *(f32x4*)dst = v;
    }
}

// role = bid%3: 0=Q (norm), 1=K (norm), 2=V (raw). g = bid/3 -> 64-pixel group.
__global__ __launch_bounds__(256) void k_qkv(
    const float* __restrict__ q_in, const float* __restrict__ kv_in,
    const ushort* __restrict__ WfQh, const ushort* __restrict__ WfQl,
    const ushort* __restrict__ WfKVh, const ushort* __restrict__ WfKVl,
    float* __restrict__ qh, float* __restrict__ kh, float* __restrict__ vv)
{
    int bid  = blockIdx.x;
    int g    = bid / 3;
    int role = bid - g * 3;
    if (role == 0)      proj_mfma16<true >(q_in,  WfQh,          WfQl,          qh, g * 64);
    else if (role == 1) proj_mfma16<true >(kv_in, WfKVh,         WfKVl,         kh, g * 64);
    else                proj_mfma16<false>(kv_in, WfKVh + 16384, WfKVl + 16384, vv, g * 64);
}

__device__ __forceinline__ int refl(int i, int n) {
    if (i < 0) i = -i;
    if (i >= n) i = 2 * n - 2 - i;
    return i;
}

// ---------------- sliding-window attention v7: split-d pair + XCD swizzle ----
// 2 lanes per (bh,pixel): lane (pl,t) handles dims [t*8, t*8+8). Logit =
// partial dot + shfl_xor(32) butterfly; softmax redundant per lane; PV
// accumulates 8 dims. Halves per-thread loads, doubles wave supply (2048
// blocks = 32 waves/CU). XCD swizzle: each XCD owns 2 contiguous (b,h)
// planes (K+V = 4 MB ~ its L2) so the 5x vertical row-reuse hits L2.
__global__ __launch_bounds__(256) void k_attn(
    const float* __restrict__ qh, const float* __restrict__ kh,
    const float* __restrict__ vv, float* __restrict__ ao)
{
    int bid = blockIdx.x;
    int swz = (bid & 7) * 256 + (bid >> 3);          // bijective on 2048
    int tid = threadIdx.x;
    int lane = tid & 63;
    int wv  = tid >> 6;                              // 0..3
    int t   = lane >> 5;                             // d-half: 0 or 1
    int pl  = lane & 31;

    int pix = swz * 128 + wv * 32 + pl;              // (bh*HW + p), 0..262143
    int p  = pix & (HW_ - 1);
    int bh = pix >> 14;
    int y = p >> 7, x = p & (W_ - 1);
    int to = t * 8;

    const float* qp = qh + ((size_t)bh * HW_ + p) * HD_ + to;
    float4 qa = *(const float4*)(qp + 0);
    float4 qb = *(const float4*)(qp + 4);

    float logit[WS_ * WS_];
    int   nidx [WS_ * WS_];
#pragma unroll
    for (int i = 0; i < WS_; ++i) {
        int ry = refl(y + i - PAD_, H_);
#pragma unroll
        for (int j = 0; j < WS_; ++j) {
            int rx = refl(x + j - PAD_, W_);
            int np_ = ry * W_ + rx;
            nidx[i*WS_ + j] = np_;
            const float* kp = kh + ((size_t)bh * HW_ + np_) * HD_ + to;
            float4 ka = *(const float4*)(kp + 0);
            float4 kb = *(const float4*)(kp + 4);
            float d = 0.f;
            d = fmaf(qa.x, ka.x, d); d = fmaf(qa.y, ka.y, d);
            d = fmaf(qa.z, ka.z, d); d = fmaf(qa.w, ka.w, d);
            d = fmaf(qb.x, kb.x, d); d = fmaf(qb.y, kb.y, d);
            d = fmaf(qb.z, kb.z, d); d = fmaf(qb.w, kb.w, d);
            logit[i*WS_ + j] = d + __shfl_xor(d, 32);   // combine d-halves
        }
    }

    float m = logit[0];
#pragma unroll
    for (int w = 1; w < WS_*WS_; ++w) m = fmaxf(m, logit[w]);
    float s = 0.f;
#pragma unroll
    for (int w = 0; w < WS_*WS_; ++w) { float e = expf(logit[w] - m); logit[w] = e; s += e; }
    float invs = 1.f / s;

    float a[8];
#pragma unroll
    for (int d = 0; d < 8; ++d) a[d] = 0.f;
#pragma unroll
    for (int w = 0; w < WS_*WS_; ++w) {
        float wt = logit[w] * invs;
        const float* vp = vv + ((size_t)bh * HW_ + nidx[w]) * HD_ + to;
        float4 va = *(const float4*)(vp + 0);
        float4 vb = *(const float4*)(vp + 4);
        a[0] = fmaf(wt, va.x, a[0]); a[1] = fmaf(wt, va.y, a[1]);
        a[2] = fmaf(wt, va.z, a[2]); a[3] = fmaf(wt, va.w, a[3]);
        a[4] = fmaf(wt, vb.x, a[4]); a[5] = fmaf(wt, vb.y, a[5]);
        a[6] = fmaf(wt, vb.z, a[6]); a[7] = fmaf(wt, vb.w, a[7]);
    }

    int b = bh >> 2, h = bh & 3;
    float* aop = ao + ((size_t)b * HW_ + p) * AD_ + h * HD_ + to;
    *(float4*)(aop + 0) = make_float4(a[0], a[1], a[2], a[3]);
    *(float4*)(aop + 4) = make_float4(a[4], a[5], a[6], a[7]);
}

// ---------------- output projection: out[b, oc, p] = sum_c WoT[c][oc] * ao[b,p,c]
__global__ __launch_bounds__(256) void k_oproj(
    const float* __restrict__ ao, const float* __restrict__ WoT,
    float* __restrict__ out)
{
    int lane = threadIdx.x & 63;
    int och  = __builtin_amdgcn_readfirstlane((int)(threadIdx.x >> 6)); // 0..3, SGPR
    int pix  = blockIdx.x * 64 + lane;                                  // 0..65535
    int b = pix >> 14;
    int p = pix & (HW_ - 1);
    const float* xp = ao + (size_t)pix * AD_;

    float acc[64];
#pragma unroll
    for (int o = 0; o < 64; ++o) acc[o] = 0.f;

    for (int c4 = 0; c4 < AD_ / 4; ++c4) {
        float4 xv = *(const float4*)(xp + c4 * 4);
#pragma unroll
        for (int cc = 0; cc < 4; ++cc) {
            float xs = (cc == 0) ? xv.x : (cc == 1) ? xv.y : (cc == 2) ? xv.z : xv.w;
            const float* wr = WoT + (size_t)(c4*4 + cc) * DIM_ + och * 64;  // uniform -> s_load
#pragma unroll
            for (int o = 0; o < 64; ++o) acc[o] = fmaf(wr[o], xs, acc[o]);
        }
    }

    float* op = out + (size_t)b * DIM_ * HW_ + (size_t)och * 64 * HW_ + p;
#pragma unroll
    for (int o = 0; o < 64; ++o) op[(size_t)o * HW_] = acc[o];
}

extern "C" void kernel_launch(void* const* d_in, const int* in_sizes, int n_in,
                              void* d_out, int out_size, void* d_ws, size_t ws_size,
                              hipStream_t stream) {
    const float* q_in  = (const float*)d_in[0];
    const float* kv_in = (const float*)d_in[1];
    const float* Wq    = (const float*)d_in[2];
    const float* Wk    = (const float*)d_in[3];
    const float* Wv    = (const float*)d_in[4];
    const float* Wo    = (const float*)d_in[5];
    float* out = (float*)d_out;

    float* wsf = (float*)d_ws;
    ushort* u    = (ushort*)wsf;
    ushort* WfQh  = u;            // 16384 shorts
    ushort* WfQl  = u + 16384;    // 16384
    ushort* WfKVh = u + 32768;    // 32768 (K: first 16384, V: last 16384)
    ushort* WfKVl = u + 65536;    // 32768  (ends at 98304 sh = 49152 floats)
    float* WoT = wsf + 49152;
    size_t tens = (size_t)B_ * HEADS_ * HW_ * HD_;   // 4,194,304 floats
    float* qh = wsf + 65536;
    float* kh = qh + tens;
    float* vv = kh + tens;
    float* ao = vv + tens;

    k_prep<<<dim3(192), dim3(256), 0, stream>>>(Wq, Wk, Wv, Wo,
                                                WfQh, WfQl, WfKVh, WfKVl, WoT);
    k_qkv<<<dim3(3072), dim3(256), 0, stream>>>(q_in, kv_in,
                                                WfQh, WfQl, WfKVh, WfKVl, qh, kh, vv);
    k_attn <<<dim3(2048), dim3(256), 0, stream>>>(qh, kh, vv, ao);
    k_oproj<<<dim3(1024), dim3(256), 0, stream>>>(ao, WoT, out);
}

// Round 10
// 130.940 us; speedup vs baseline: 1.7948x; 1.0176x over previous
//
#include <hip/hip_runtime.h>
#include <hip/hip_bf16.h>
#include <math.h>

#define B_ 4
#define DIM_ 256
#define H_ 128
#define W_ 128
#define HW_ (H_ * W_)
#define AD_ 64
#define HEADS_ 4
#define HD_ 16
#define WS_ 5
#define PAD_ 2

typedef __attribute__((ext_vector_type(8))) short short8;
typedef __attribute__((ext_vector_type(4))) float f32x4;

__device__ __forceinline__ ushort f2bf(float f) {
    unsigned u = __builtin_bit_cast(unsigned, f);
    unsigned r = u + 0x7FFFu + ((u >> 16) & 1u);
    return (ushort)(r >> 16);
}
__device__ __forceinline__ float bf2f(ushort h) {
    return __builtin_bit_cast(float, (unsigned)h << 16);
}

// async global->LDS, 16B per lane. LDS dest must be wave-uniform base + lane*16.
__device__ __forceinline__ void gl16(const void* g, void* l) {
    __builtin_amdgcn_global_load_lds(
        (const __attribute__((address_space(1))) unsigned int*)g,
        (__attribute__((address_space(3))) unsigned int*)l, 16, 0, 0);
}

// ---------------- prep: WoT for oproj + fragment-ordered bf16 hi/lo weights --
// A-fragment layout for mfma_f32_16x16x32_bf16: lane l holds A[o=l&15][c] for
// 8 c's = kc*32 + (l>>4)*8 + j. The SAME (lane,j)->c map is used for the B
// path in k_qkv, so the contraction is correct under any consistent k-perm.
__global__ __launch_bounds__(256) void k_prep(
    const float* __restrict__ Wq, const float* __restrict__ Wk,
    const float* __restrict__ Wv, const float* __restrict__ Wo,
    ushort* __restrict__ WfQh, ushort* __restrict__ WfQl,
    ushort* __restrict__ WfKVh, ushort* __restrict__ WfKVl,
    float* __restrict__ WoT)
{
    int i = blockIdx.x * 256 + threadIdx.x;          // 0 .. 49151
    if (i < AD_ * DIM_) {                            // WoT: (256,64) -> (64,256)
        int o2 = i / AD_, c2 = i % AD_;
        WoT[c2 * DIM_ + o2] = Wo[i];
    }
    if (i < 16384) {                                 // Q frags: 4mt*8kc*64l*8j
        int j = i & 7, l = (i >> 3) & 63, kc = (i >> 9) & 7, mt = i >> 12;
        int o = mt * 16 + (l & 15);
        int c = kc * 32 + ((l >> 4) & 3) * 8 + j;
        float wv = Wq[o * DIM_ + c];
        ushort h = f2bf(wv);
        WfQh[i] = h;
        WfQl[i] = f2bf(wv - bf2f(h));
    } else if (i < 49152) {                          // KV frags: 8mt (K:0-3, V:4-7)
        int ii = i - 16384;
        int j = ii & 7, l = (ii >> 3) & 63, kc = (ii >> 9) & 7, mt = ii >> 12;
        const float* Ws = (mt < 4) ? Wk : Wv;
        int o = (mt & 3) * 16 + (l & 15);
        int c = kc * 32 + ((l >> 4) & 3) * 8 + j;
        float wv = Ws[o * DIM_ + c];
        ushort h = f2bf(wv);
        WfKVh[ii] = h;
        WfKVl[ii] = f2bf(wv - bf2f(h));
    }
}

// ---------------- QKV projection v10: m97-style LDS pipeline (R9 fixed) ------
// Block = 4 waves = 128 px x 64 out (one role), K = 256 in 8 chunks of 32c.
// Per chunk, coalesced global_load_lds(16B) staging (double-buffered):
//   X tile [32c][128px] f32 = 16 KB: 1024 segs, c = s>>5, seg = s&31
//     (R9 BUG was c = s>>3 / seg = s&7 -> OOB reads + wrong layout)
//   A tile: 8 slices of 1KB ({h,l} x 4mt), lane-linear LDS dest (2 insts/thr)
// 2-phase: issue next-chunk stages -> compute current -> __syncthreads.
// Same fragment maps + per-acc MFMA order as v6-v8 -> bitwise-identical out.
__global__ __launch_bounds__(256) void k_qkv(
    const float* __restrict__ q_in, const float* __restrict__ kv_in,
    const ushort* __restrict__ WfQh, const ushort* __restrict__ WfQl,
    const ushort* __restrict__ WfKVh, const ushort* __restrict__ WfKVl,
    float* __restrict__ qh, float* __restrict__ kh, float* __restrict__ vv)
{
    __shared__ float  Xl[2][32 * 128];     // 32 KB dbuf
    __shared__ ushort Al[2][512 * 8];      // 16 KB dbuf: [k(h/l)][mt][lane][8]

    int bid  = blockIdx.x;
    int g    = bid / 3;
    int role = bid - g * 3;                // 0=Q 1=K 2=V
    int b    = g >> 7;                     // batch (128 groups per batch)
    int p0   = (g & 127) * 128;            // pixel base within batch

    const float*  xsrc = (role == 0) ? q_in : kv_in;
    const ushort* Wh = (role == 0) ? WfQh : (role == 1) ? WfKVh : (WfKVh + 16384);
    const ushort* Wl = (role == 0) ? WfQl : (role == 1) ? WfKVl : (WfKVl + 16384);
    float* outp = (role == 0) ? qh : (role == 1) ? kh : vv;
    bool norm = (role < 2);                // uniform per block

    int tid  = threadIdx.x;
    int lane = tid & 63;
    int wid  = __builtin_amdgcn_readfirstlane(tid >> 6);
    int lr = lane & 15, kg = lane >> 4;
    int mtw = tid >> 6;                    // staging: this wave's mt slice

    const float* xbase = xsrc + ((size_t)b * DIM_ << 14) + p0;

    // ---- prologue: stage chunk 0 into buf 0
    {
#pragma unroll
        for (int i = 0; i < 4; ++i) {
            int s = i * 256 + tid;         // 0..1023: c = s>>5, 16B-seg = s&31
            gl16(xbase + (size_t)(s >> 5) * HW_ + (s & 31) * 4, &Xl[0][s * 4]);
        }
#pragma unroll
        for (int k = 0; k < 2; ++k) {      // k=0: h slice mt=wid, k=1: l slice
            int s = k * 256 + tid;
            const ushort* wsrc = (k ? Wl : Wh) + ((mtw * 8 + 0) << 9) + (tid & 63) * 8;
            gl16(wsrc, &Al[0][s * 8]);
        }
    }
    __syncthreads();

    f32x4 acc[4][2];
#pragma unroll
    for (int mt = 0; mt < 4; ++mt)
#pragma unroll
        for (int nt = 0; nt < 2; ++nt) {
            f32x4 z = {0.f, 0.f, 0.f, 0.f};
            acc[mt][nt] = z;
        }

    for (int kc = 0; kc < 8; ++kc) {
        int buf = kc & 1;
        if (kc < 7) {                      // issue next-chunk stages early
            int nb = buf ^ 1, nk = kc + 1;
#pragma unroll
            for (int i = 0; i < 4; ++i) {
                int s = i * 256 + tid;     // c = s>>5 (0..31), seg = s&31
                gl16(xbase + (size_t)(nk * 32 + (s >> 5)) * HW_ + (s & 31) * 4,
                     &Xl[nb][s * 4]);
            }
#pragma unroll
            for (int k = 0; k < 2; ++k) {
                int s = k * 256 + tid;
                const ushort* wsrc = (k ? Wl : Wh) + ((mtw * 8 + nk) << 9) + (tid & 63) * 8;
                gl16(wsrc, &Al[nb][s * 8]);
            }
        }

        // ---- compute current chunk from LDS
        short8 bh[2], bl[2];
#pragma unroll
        for (int nt = 0; nt < 2; ++nt) {
            float xv[8];
#pragma unroll
            for (int j = 0; j < 8; ++j)
                xv[j] = Xl[buf][(kg * 8 + j) * 128 + wid * 32 + nt * 16 + lr];
#pragma unroll
            for (int j = 0; j < 8; ++j) {
                ushort h = f2bf(xv[j]);
                bh[nt][j] = (short)h;
                bl[nt][j] = (short)f2bf(xv[j] - bf2f(h));
            }
        }
#pragma unroll
        for (int mt = 0; mt < 4; ++mt) {
            short8 ah = *(const short8*)&Al[buf][(mt * 64 + lane) * 8];
            short8 al = *(const short8*)&Al[buf][(256 + mt * 64 + lane) * 8];
#pragma unroll
            for (int nt = 0; nt < 2; ++nt) {
                acc[mt][nt] = __builtin_amdgcn_mfma_f32_16x16x32_bf16(ah, bh[nt], acc[mt][nt], 0, 0, 0);
                acc[mt][nt] = __builtin_amdgcn_mfma_f32_16x16x32_bf16(ah, bl[nt], acc[mt][nt], 0, 0, 0);
                acc[mt][nt] = __builtin_amdgcn_mfma_f32_16x16x32_bf16(al, bh[nt], acc[mt][nt], 0, 0, 0);
            }
        }
        __syncthreads();                   // drains stages, protects buf reuse
    }

    // ---- epilogue (R7 layout): l2norm + store
    int pr = p0 + wid * 32;
#pragma unroll
    for (int mt = 0; mt < 4; ++mt) {
#pragma unroll
        for (int nt = 0; nt < 2; ++nt) {
            f32x4 v = acc[mt][nt];
            if (norm) {                    // l2norm over the head's 16 rows
                float s = v.x * v.x + v.y * v.y + v.z * v.z + v.w * v.w;
                s += __shfl_xor(s, 16);    // lanes {lr, lr+16, lr+32, lr+48}
                s += __shfl_xor(s, 32);
                float inv = 1.f / fmaxf(sqrtf(s), 1e-12f);
                v.x *= inv; v.y *= inv; v.z *= inv; v.w *= inv;
            }
            float* dst = outp
                + (((size_t)(b * HEADS_ + mt) << 14) + pr + nt * 16 + lr) * HD_ + kg * 4;
            *(f32x4*)dst = v;
        }
    }
}

__device__ __forceinline__ int refl(int i, int n) {
    if (i < 0) i = -i;
    if (i >= n) i = 2 * n - 2 - i;
    return i;
}

// ---------------- sliding-window attention v7: split-d pair + XCD swizzle ----
__global__ __launch_bounds__(256) void k_attn(
    const float* __restrict__ qh, const float* __restrict__ kh,
    const float* __restrict__ vv, float* __restrict__ ao)
{
    int bid = blockIdx.x;
    int swz = (bid & 7) * 256 + (bid >> 3);          // bijective on 2048
    int tid = threadIdx.x;
    int lane = tid & 63;
    int wv  = tid >> 6;                              // 0..3
    int t   = lane >> 5;                             // d-half: 0 or 1
    int pl  = lane & 31;

    int pix = swz * 128 + wv * 32 + pl;              // (bh*HW + p), 0..262143
    int p  = pix & (HW_ - 1);
    int bh = pix >> 14;
    int y = p >> 7, x = p & (W_ - 1);
    int to = t * 8;

    const float* qp = qh + ((size_t)bh * HW_ + p) * HD_ + to;
    float4 qa = *(const float4*)(qp + 0);
    float4 qb = *(const float4*)(qp + 4);

    float logit[WS_ * WS_];
    int   nidx [WS_ * WS_];
#pragma unroll
    for (int i = 0; i < WS_; ++i) {
        int ry = refl(y + i - PAD_, H_);
#pragma unroll
        for (int j = 0; j < WS_; ++j) {
            int rx = refl(x + j - PAD_, W_);
            int np_ = ry * W_ + rx;
            nidx[i*WS_ + j] = np_;
            const float* kp = kh + ((size_t)bh * HW_ + np_) * HD_ + to;
            float4 ka = *(const float4*)(kp + 0);
            float4 kb = *(const float4*)(kp + 4);
            float d = 0.f;
            d = fmaf(qa.x, ka.x, d); d = fmaf(qa.y, ka.y, d);
            d = fmaf(qa.z, ka.z, d); d = fmaf(qa.w, ka.w, d);
            d = fmaf(qb.x, kb.x, d); d = fmaf(qb.y, kb.y, d);
            d = fmaf(qb.z, kb.z, d); d = fmaf(qb.w, kb.w, d);
            logit[i*WS_ + j] = d + __shfl_xor(d, 32);   // combine d-halves
        }
    }

    float m = logit[0];
#pragma unroll
    for (int w = 1; w < WS_*WS_; ++w) m = fmaxf(m, logit[w]);
    float s = 0.f;
#pragma unroll
    for (int w = 0; w < WS_*WS_; ++w) { float e = expf(logit[w] - m); logit[w] = e; s += e; }
    float invs = 1.f / s;

    float a[8];
#pragma unroll
    for (int d = 0; d < 8; ++d) a[d] = 0.f;
#pragma unroll
    for (int w = 0; w < WS_*WS_; ++w) {
        float wt = logit[w] * invs;
        const float* vp = vv + ((size_t)bh * HW_ + nidx[w]) * HD_ + to;
        float4 va = *(const float4*)(vp + 0);
        float4 vb = *(const float4*)(vp + 4);
        a[0] = fmaf(wt, va.x, a[0]); a[1] = fmaf(wt, va.y, a[1]);
        a[2] = fmaf(wt, va.z, a[2]); a[3] = fmaf(wt, va.w, a[3]);
        a[4] = fmaf(wt, vb.x, a[4]); a[5] = fmaf(wt, vb.y, a[5]);
        a[6] = fmaf(wt, vb.z, a[6]); a[7] = fmaf(wt, vb.w, a[7]);
    }

    int b = bh >> 2, h = bh & 3;
    float* aop = ao + ((size_t)b * HW_ + p) * AD_ + h * HD_ + to;
    *(float4*)(aop + 0) = make_float4(a[0], a[1], a[2], a[3]);
    *(float4*)(aop + 4) = make_float4(a[4], a[5], a[6], a[7]);
}

// ---------------- output projection: out[b, oc, p] = sum_c WoT[c][oc] * ao[b,p,c]
__global__ __launch_bounds__(256) void k_oproj(
    const float* __restrict__ ao, const float* __restrict__ WoT,
    float* __restrict__ out)
{
    int lane = threadIdx.x & 63;
    int och  = __builtin_amdgcn_readfirstlane((int)(threadIdx.x >> 6)); // 0..3, SGPR
    int pix  = blockIdx.x * 64 + lane;                                  // 0..65535
    int b = pix >> 14;
    int p = pix & (HW_ - 1);
    const float* xp = ao + (size_t)pix * AD_;

    float acc[64];
#pragma unroll
    for (int o = 0; o < 64; ++o) acc[o] = 0.f;

    for (int c4 = 0; c4 < AD_ / 4; ++c4) {
        float4 xv = *(const float4*)(xp + c4 * 4);
#pragma unroll
        for (int cc = 0; cc < 4; ++cc) {
            float xs = (cc == 0) ? xv.x : (cc == 1) ? xv.y : (cc == 2) ? xv.z : xv.w;
            const float* wr = WoT + (size_t)(c4*4 + cc) * DIM_ + och * 64;  // uniform -> s_load
#pragma unroll
            for (int o = 0; o < 64; ++o) acc[o] = fmaf(wr[o], xs, acc[o]);
        }
    }

    float* op = out + (size_t)b * DIM_ * HW_ + (size_t)och * 64 * HW_ + p;
#pragma unroll
    for (int o = 0; o < 64; ++o) op[(size_t)o * HW_] = acc[o];
}

extern "C" void kernel_launch(void* const* d_in, const int* in_sizes, int n_in,
                              void* d_out, int out_size, void* d_ws, size_t ws_size,
                              hipStream_t stream) {
    const float* q_in  = (const float*)d_in[0];
    const float* kv_in = (const float*)d_in[1];
    const float* Wq    = (const float*)d_in[2];
    const float* Wk    = (const float*)d_in[3];
    const float* Wv    = (const float*)d_in[4];
    const float* Wo    = (const float*)d_in[5];
    float* out = (float*)d_out;

    float* wsf = (float*)d_ws;
    ushort* u    = (ushort*)wsf;
    ushort* WfQh  = u;            // 16384 shorts
    ushort* WfQl  = u + 16384;    // 16384
    ushort* WfKVh = u + 32768;    // 32768 (K: first 16384, V: last 16384)
    ushort* WfKVl = u + 65536;    // 32768  (ends at 98304 sh = 49152 floats)
    float* WoT = wsf + 49152;
    size_t tens = (size_t)B_ * HEADS_ * HW_ * HD_;   // 4,194,304 floats
    float* qh = wsf + 65536;
    float* kh = qh + tens;
    float* vv = kh + tens;
    float* ao = vv + tens;

    k_prep<<<dim3(192), dim3(256), 0, stream>>>(Wq, Wk, Wv, Wo,
                                                WfQh, WfQl, WfKVh, WfKVl, WoT);
    k_qkv<<<dim3(1536), dim3(256), 0, stream>>>(q_in, kv_in,
                                                WfQh, WfQl, WfKVh, WfKVl, qh, kh, vv);
    k_attn <<<dim3(2048), dim3(256), 0, stream>>>(qh, kh, vv, ao);
    k_oproj<<<dim3(1024), dim3(256), 0, stream>>>(ao, WoT, out);
}

// Round 11
// 129.604 us; speedup vs baseline: 1.8133x; 1.0103x over previous
//
#include <hip/hip_runtime.h>
#include <hip/hip_bf16.h>
#include <math.h>

#define B_ 4
#define DIM_ 256
#define H_ 128
#define W_ 128
#define HW_ (H_ * W_)
#define AD_ 64
#define HEADS_ 4
#define HD_ 16
#define WS_ 5
#define PAD_ 2

typedef __attribute__((ext_vector_type(8))) short short8;
typedef __attribute__((ext_vector_type(4))) float f32x4;

__device__ __forceinline__ ushort f2bf(float f) {
    unsigned u = __builtin_bit_cast(unsigned, f);
    unsigned r = u + 0x7FFFu + ((u >> 16) & 1u);
    return (ushort)(r >> 16);
}
__device__ __forceinline__ float bf2f(ushort h) {
    return __builtin_bit_cast(float, (unsigned)h << 16);
}

// async global->LDS, 16B per lane. LDS dest must be wave-uniform base + lane*16.
__device__ __forceinline__ void gl16(const void* g, void* l) {
    __builtin_amdgcn_global_load_lds(
        (const __attribute__((address_space(1))) unsigned int*)g,
        (__attribute__((address_space(3))) unsigned int*)l, 16, 0, 0);
}

// ---------------- prep: WoT for oproj + fragment-ordered bf16 hi/lo weights --
// A-fragment layout for mfma_f32_16x16x32_bf16: lane l holds A[o=l&15][c] for
// 8 c's = kc*32 + (l>>4)*8 + j. The SAME (lane,j)->c map is used for the B
// path in k_qkv, so the contraction is correct under any consistent k-perm.
__global__ __launch_bounds__(256) void k_prep(
    const float* __restrict__ Wq, const float* __restrict__ Wk,
    const float* __restrict__ Wv, const float* __restrict__ Wo,
    ushort* __restrict__ WfQh, ushort* __restrict__ WfQl,
    ushort* __restrict__ WfKVh, ushort* __restrict__ WfKVl,
    float* __restrict__ WoT)
{
    int i = blockIdx.x * 256 + threadIdx.x;          // 0 .. 49151
    if (i < AD_ * DIM_) {                            // WoT: (256,64) -> (64,256)
        int o2 = i / AD_, c2 = i % AD_;
        WoT[c2 * DIM_ + o2] = Wo[i];
    }
    if (i < 16384) {                                 // Q frags: 4mt*8kc*64l*8j
        int j = i & 7, l = (i >> 3) & 63, kc = (i >> 9) & 7, mt = i >> 12;
        int o = mt * 16 + (l & 15);
        int c = kc * 32 + ((l >> 4) & 3) * 8 + j;
        float wv = Wq[o * DIM_ + c];
        ushort h = f2bf(wv);
        WfQh[i] = h;
        WfQl[i] = f2bf(wv - bf2f(h));
    } else if (i < 49152) {                          // KV frags: 8mt (K:0-3, V:4-7)
        int ii = i - 16384;
        int j = ii & 7, l = (ii >> 3) & 63, kc = (ii >> 9) & 7, mt = ii >> 12;
        const float* Ws = (mt < 4) ? Wk : Wv;
        int o = (mt & 3) * 16 + (l & 15);
        int c = kc * 32 + ((l >> 4) & 3) * 8 + j;
        float wv = Ws[o * DIM_ + c];
        ushort h = f2bf(wv);
        WfKVh[ii] = h;
        WfKVl[ii] = f2bf(wv - bf2f(h));
    }
}

// ---------------- QKV projection v11: barrier-free per-wave pipeline ---------
// Block = 4 waves; wave = 64 out x 32 px, K = 256 in 8 chunks of 32c.
//  - X: per-WAVE-private LDS subtile [2][32c][32px] (32 KB/block -> 5 blk/CU).
//    Staged via 4 coalesced gl16/chunk. No data shared across waves.
//  - A-frags: direct global->VGPR 16B loads (coalesced, L2-hot 96 KB).
//  - NO __syncthreads. Ordering per wave: A-loads first, then 4 gl16 for the
//    NEXT chunk, then s_waitcnt vmcnt(4): drains prev-chunk gl16s (and the
//    consumed A stream) while keeping the 4 new loads in flight across the
//    whole compute phase -- the counted-vmcnt (T4) fix for R10's barrier
//    drain-to-0 stall. sched_barrier(0) per guide rule #18.
// Same fragment maps + per-acc MFMA order as v6-v10 -> bitwise-identical out.
__global__ __launch_bounds__(256) void k_qkv(
    const float* __restrict__ q_in, const float* __restrict__ kv_in,
    const ushort* __restrict__ WfQh, const ushort* __restrict__ WfQl,
    const ushort* __restrict__ WfKVh, const ushort* __restrict__ WfKVl,
    float* __restrict__ qh, float* __restrict__ kh, float* __restrict__ vv)
{
    __shared__ float Xl[2][4][32 * 32];    // [buf][wave][c*32+px] = 32 KB

    int bid  = blockIdx.x;
    int g    = bid / 3;
    int role = bid - g * 3;                // 0=Q 1=K 2=V
    int b    = g >> 7;                     // batch (128 groups per batch)
    int p0   = (g & 127) * 128;            // pixel base within batch

    const float*  xsrc = (role == 0) ? q_in : kv_in;
    const ushort* Wh = (role == 0) ? WfQh : (role == 1) ? WfKVh : (WfKVh + 16384);
    const ushort* Wl = (role == 0) ? WfQl : (role == 1) ? WfKVl : (WfKVl + 16384);
    float* outp = (role == 0) ? qh : (role == 1) ? kh : vv;
    bool norm = (role < 2);                // uniform per block

    int tid  = threadIdx.x;
    int lane = tid & 63;
    int wid  = __builtin_amdgcn_readfirstlane(tid >> 6);
    int lr = lane & 15, kg = lane >> 4;

    // wave's 32 pixel columns
    const float* xw = xsrc + ((size_t)b * DIM_ << 14) + p0 + wid * 32;

    // ---- prologue: stage chunk 0 into buf 0 (per wave: 4 gl16)
#pragma unroll
    for (int i = 0; i < 4; ++i) {
        int s = i * 64 + lane;             // 0..255: r = s>>3 (c-row), seg = s&7
        gl16(xw + (size_t)(s >> 3) * HW_ + (s & 7) * 4, &Xl[0][wid][s * 4]);
    }

    f32x4 acc[4][2];
#pragma unroll
    for (int mt = 0; mt < 4; ++mt)
#pragma unroll
        for (int nt = 0; nt < 2; ++nt) {
            f32x4 z = {0.f, 0.f, 0.f, 0.f};
            acc[mt][nt] = z;
        }

    for (int kc = 0; kc < 8; ++kc) {
        int buf = kc & 1;

        // A-frag register loads for THIS chunk (issue before staging so the
        // vmcnt(4) below leaves only the new gl16s in flight)
        short8 ah[4], al[4];
#pragma unroll
        for (int mt = 0; mt < 4; ++mt) {
            ah[mt] = *(const short8*)(Wh + (((mt * 8 + kc) << 6) + lane) * 8);
            al[mt] = *(const short8*)(Wl + (((mt * 8 + kc) << 6) + lane) * 8);
        }

        if (kc < 7) {                      // stage chunk kc+1 -> other buf
#pragma unroll
            for (int i = 0; i < 4; ++i) {
                int s = i * 64 + lane;
                gl16(xw + (size_t)((kc + 1) * 32 + (s >> 3)) * HW_ + (s & 7) * 4,
                     &Xl[buf ^ 1][wid][s * 4]);
            }
        }

        // prev-chunk gl16s (this buf) have landed; 4 newest stay in flight
        asm volatile("s_waitcnt vmcnt(4)" ::: "memory");
        __builtin_amdgcn_sched_barrier(0);

        // ---- compute current chunk from this wave's private LDS tile
        short8 bh[2], bl[2];
#pragma unroll
        for (int nt = 0; nt < 2; ++nt) {
            float xv[8];
#pragma unroll
            for (int j = 0; j < 8; ++j)
                xv[j] = Xl[buf][wid][(kg * 8 + j) * 32 + nt * 16 + lr];
#pragma unroll
            for (int j = 0; j < 8; ++j) {
                ushort h = f2bf(xv[j]);
                bh[nt][j] = (short)h;
                bl[nt][j] = (short)f2bf(xv[j] - bf2f(h));
            }
        }
#pragma unroll
        for (int mt = 0; mt < 4; ++mt) {
#pragma unroll
            for (int nt = 0; nt < 2; ++nt) {
                acc[mt][nt] = __builtin_amdgcn_mfma_f32_16x16x32_bf16(ah[mt], bh[nt], acc[mt][nt], 0, 0, 0);
                acc[mt][nt] = __builtin_amdgcn_mfma_f32_16x16x32_bf16(ah[mt], bl[nt], acc[mt][nt], 0, 0, 0);
                acc[mt][nt] = __builtin_amdgcn_mfma_f32_16x16x32_bf16(al[mt], bh[nt], acc[mt][nt], 0, 0, 0);
            }
        }
        // no barrier: X tile is wave-private; lgkm waits order ds_read vs reuse
    }

    // ---- epilogue (R7 layout): l2norm + store
    int pr = p0 + wid * 32;
#pragma unroll
    for (int mt = 0; mt < 4; ++mt) {
#pragma unroll
        for (int nt = 0; nt < 2; ++nt) {
            f32x4 v = acc[mt][nt];
            if (norm) {                    // l2norm over the head's 16 rows
                float s = v.x * v.x + v.y * v.y + v.z * v.z + v.w * v.w;
                s += __shfl_xor(s, 16);    // lanes {lr, lr+16, lr+32, lr+48}
                s += __shfl_xor(s, 32);
                float inv = 1.f / fmaxf(sqrtf(s), 1e-12f);
                v.x *= inv; v.y *= inv; v.z *= inv; v.w *= inv;
            }
            float* dst = outp
                + (((size_t)(b * HEADS_ + mt) << 14) + pr + nt * 16 + lr) * HD_ + kg * 4;
            *(f32x4*)dst = v;
        }
    }
}

__device__ __forceinline__ int refl(int i, int n) {
    if (i < 0) i = -i;
    if (i >= n) i = 2 * n - 2 - i;
    return i;
}

// ---------------- sliding-window attention v7: split-d pair + XCD swizzle ----
__global__ __launch_bounds__(256) void k_attn(
    const float* __restrict__ qh, const float* __restrict__ kh,
    const float* __restrict__ vv, float* __restrict__ ao)
{
    int bid = blockIdx.x;
    int swz = (bid & 7) * 256 + (bid >> 3);          // bijective on 2048
    int tid = threadIdx.x;
    int lane = tid & 63;
    int wv  = tid >> 6;                              // 0..3
    int t   = lane >> 5;                             // d-half: 0 or 1
    int pl  = lane & 31;

    int pix = swz * 128 + wv * 32 + pl;              // (bh*HW + p), 0..262143
    int p  = pix & (HW_ - 1);
    int bh = pix >> 14;
    int y = p >> 7, x = p & (W_ - 1);
    int to = t * 8;

    const float* qp = qh + ((size_t)bh * HW_ + p) * HD_ + to;
    float4 qa = *(const float4*)(qp + 0);
    float4 qb = *(const float4*)(qp + 4);

    float logit[WS_ * WS_];
    int   nidx [WS_ * WS_];
#pragma unroll
    for (int i = 0; i < WS_; ++i) {
        int ry = refl(y + i - PAD_, H_);
#pragma unroll
        for (int j = 0; j < WS_; ++j) {
            int rx = refl(x + j - PAD_, W_);
            int np_ = ry * W_ + rx;
            nidx[i*WS_ + j] = np_;
            const float* kp = kh + ((size_t)bh * HW_ + np_) * HD_ + to;
            float4 ka = *(const float4*)(kp + 0);
            float4 kb = *(const float4*)(kp + 4);
            float d = 0.f;
            d = fmaf(qa.x, ka.x, d); d = fmaf(qa.y, ka.y, d);
            d = fmaf(qa.z, ka.z, d); d = fmaf(qa.w, ka.w, d);
            d = fmaf(qb.x, kb.x, d); d = fmaf(qb.y, kb.y, d);
            d = fmaf(qb.z, kb.z, d); d = fmaf(qb.w, kb.w, d);
            logit[i*WS_ + j] = d + __shfl_xor(d, 32);   // combine d-halves
        }
    }

    float m = logit[0];
#pragma unroll
    for (int w = 1; w < WS_*WS_; ++w) m = fmaxf(m, logit[w]);
    float s = 0.f;
#pragma unroll
    for (int w = 0; w < WS_*WS_; ++w) { float e = expf(logit[w] - m); logit[w] = e; s += e; }
    float invs = 1.f / s;

    float a[8];
#pragma unroll
    for (int d = 0; d < 8; ++d) a[d] = 0.f;
#pragma unroll
    for (int w = 0; w < WS_*WS_; ++w) {
        float wt = logit[w] * invs;
        const float* vp = vv + ((size_t)bh * HW_ + nidx[w]) * HD_ + to;
        float4 va = *(const float4*)(vp + 0);
        float4 vb = *(const float4*)(vp + 4);
        a[0] = fmaf(wt, va.x, a[0]); a[1] = fmaf(wt, va.y, a[1]);
        a[2] = fmaf(wt, va.z, a[2]); a[3] = fmaf(wt, va.w, a[3]);
        a[4] = fmaf(wt, vb.x, a[4]); a[5] = fmaf(wt, vb.y, a[5]);
        a[6] = fmaf(wt, vb.z, a[6]); a[7] = fmaf(wt, vb.w, a[7]);
    }

    int b = bh >> 2, h = bh & 3;
    float* aop = ao + ((size_t)b * HW_ + p) * AD_ + h * HD_ + to;
    *(float4*)(aop + 0) = make_float4(a[0], a[1], a[2], a[3]);
    *(float4*)(aop + 4) = make_float4(a[4], a[5], a[6], a[7]);
}

// ---------------- output projection: out[b, oc, p] = sum_c WoT[c][oc] * ao[b,p,c]
__global__ __launch_bounds__(256) void k_oproj(
    const float* __restrict__ ao, const float* __restrict__ WoT,
    float* __restrict__ out)
{
    int lane = threadIdx.x & 63;
    int och  = __builtin_amdgcn_readfirstlane((int)(threadIdx.x >> 6)); // 0..3, SGPR
    int pix  = blockIdx.x * 64 + lane;                                  // 0..65535
    int b = pix >> 14;
    int p = pix & (HW_ - 1);
    const float* xp = ao + (size_t)pix * AD_;

    float acc[64];
#pragma unroll
    for (int o = 0; o < 64; ++o) acc[o] = 0.f;

    for (int c4 = 0; c4 < AD_ / 4; ++c4) {
        float4 xv = *(const float4*)(xp + c4 * 4);
#pragma unroll
        for (int cc = 0; cc < 4; ++cc) {
            float xs = (cc == 0) ? xv.x : (cc == 1) ? xv.y : (cc == 2) ? xv.z : xv.w;
            const float* wr = WoT + (size_t)(c4*4 + cc) * DIM_ + och * 64;  // uniform -> s_load
#pragma unroll
            for (int o = 0; o < 64; ++o) acc[o] = fmaf(wr[o], xs, acc[o]);
        }
    }

    float* op = out + (size_t)b * DIM_ * HW_ + (size_t)och * 64 * HW_ + p;
#pragma unroll
    for (int o = 0; o < 64; ++o) op[(size_t)o * HW_] = acc[o];
}

extern "C" void kernel_launch(void* const* d_in, const int* in_sizes, int n_in,
                              void* d_out, int out_size, void* d_ws, size_t ws_size,
                              hipStream_t stream) {
    const float* q_in  = (const float*)d_in[0];
    const float* kv_in = (const float*)d_in[1];
    const float* Wq    = (const float*)d_in[2];
    const float* Wk    = (const float*)d_in[3];
    const float* Wv    = (const float*)d_in[4];
    const float* Wo    = (const float*)d_in[5];
    float* out = (float*)d_out;

    float* wsf = (float*)d_ws;
    ushort* u    = (ushort*)wsf;
    ushort* WfQh  = u;            // 16384 shorts
    ushort* WfQl  = u + 16384;    // 16384
    ushort* WfKVh = u + 32768;    // 32768 (K: first 16384, V: last 16384)
    ushort* WfKVl = u + 65536;    // 32768  (ends at 98304 sh = 49152 floats)
    float* WoT = wsf + 49152;
    size_t tens = (size_t)B_ * HEADS_ * HW_ * HD_;   // 4,194,304 floats
    float* qh = wsf + 65536;
    float* kh = qh + tens;
    float* vv = kh + tens;
    float* ao = vv + tens;

    k_prep<<<dim3(192), dim3(256), 0, stream>>>(Wq, Wk, Wv, Wo,
                                                WfQh, WfQl, WfKVh, WfKVl, WoT);
    k_qkv<<<dim3(1536), dim3(256), 0, stream>>>(q_in, kv_in,
                                                WfQh, WfQl, WfKVh, WfKVl, qh, kh, vv);
    k_attn <<<dim3(2048), dim3(256), 0, stream>>>(qh, kh, vv, ao);
    k_oproj<<<dim3(1024), dim3(256), 0, stream>>>(ao, WoT, out);
}

// Round 12
// 123.163 us; speedup vs baseline: 1.9081x; 1.0523x over previous
//
#include <hip/hip_runtime.h>
#include <hip/hip_bf16.h>
#include <math.h>

#define B_ 4
#define DIM_ 256
#define H_ 128
#define W_ 128
#define HW_ (H_ * W_)
#define AD_ 64
#define HEADS_ 4
#define HD_ 16
#define WS_ 5
#define PAD_ 2

typedef __attribute__((ext_vector_type(8))) short short8;
typedef __attribute__((ext_vector_type(4))) float f32x4;

__device__ __forceinline__ ushort f2bf(float f) {
    unsigned u = __builtin_bit_cast(unsigned, f);
    unsigned r = u + 0x7FFFu + ((u >> 16) & 1u);
    return (ushort)(r >> 16);
}
__device__ __forceinline__ float bf2f(ushort h) {
    return __builtin_bit_cast(float, (unsigned)h << 16);
}

// async global->LDS, 16B per lane. LDS dest must be wave-uniform base + lane*16.
__device__ __forceinline__ void gl16(const void* g, void* l) {
    __builtin_amdgcn_global_load_lds(
        (const __attribute__((address_space(1))) unsigned int*)g,
        (__attribute__((address_space(3))) unsigned int*)l, 16, 0, 0);
}

// ---------------- prep: fragment-ordered bf16 hi/lo weights (Q/K/V/O) --------
// A-fragment layout for mfma_f32_16x16x32_bf16: lane l holds A[o=l&15][c] for
// 8 c's = kc*32 + (l>>4)*8 + j. The SAME (lane,j)->c map is used for every B
// path, so each contraction is correct under a consistent k-perm.
__global__ __launch_bounds__(256) void k_prep(
    const float* __restrict__ Wq, const float* __restrict__ Wk,
    const float* __restrict__ Wv, const float* __restrict__ Wo,
    ushort* __restrict__ WfQh, ushort* __restrict__ WfQl,
    ushort* __restrict__ WfKVh, ushort* __restrict__ WfKVl,
    ushort* __restrict__ WoFh, ushort* __restrict__ WoFl)
{
    int i = blockIdx.x * 256 + threadIdx.x;          // 0 .. 49151
    if (i < 16384) {                                 // Q frags: 4mt*8kc*64l*8j
        int j = i & 7, l = (i >> 3) & 63, kc = (i >> 9) & 7, mt = i >> 12;
        int o = mt * 16 + (l & 15);
        int c = kc * 32 + ((l >> 4) & 3) * 8 + j;
        float wv = Wq[o * DIM_ + c];
        ushort h = f2bf(wv);
        WfQh[i] = h;
        WfQl[i] = f2bf(wv - bf2f(h));
        // Wo frags: 16 mtg * 2 kc * 64 l * 8 j (K=64)
        int kco = (i >> 9) & 1, mtg = i >> 10;
        int oo = mtg * 16 + (l & 15);                // Wo row (out channel)
        int co = kco * 32 + ((l >> 4) & 3) * 8 + j;  // Wo col (attn channel)
        float wo = Wo[oo * AD_ + co];
        ushort ho = f2bf(wo);
        WoFh[i] = ho;
        WoFl[i] = f2bf(wo - bf2f(ho));
    } else if (i < 49152) {                          // KV frags: 8mt (K:0-3, V:4-7)
        int ii = i - 16384;
        int j = ii & 7, l = (ii >> 3) & 63, kc = (ii >> 9) & 7, mt = ii >> 12;
        const float* Ws = (mt < 4) ? Wk : Wv;
        int o = (mt & 3) * 16 + (l & 15);
        int c = kc * 32 + ((l >> 4) & 3) * 8 + j;
        float wv = Ws[o * DIM_ + c];
        ushort h = f2bf(wv);
        WfKVh[ii] = h;
        WfKVl[ii] = f2bf(wv - bf2f(h));
    }
}

// convert one 32c x (2x16px) B tile from this wave's LDS X subtile
__device__ __forceinline__ void conv_b(const float* Xw, int lr, int kg,
                                       short8* bh, short8* bl)
{
#pragma unroll
    for (int nt = 0; nt < 2; ++nt) {
        float xv[8];
#pragma unroll
        for (int j = 0; j < 8; ++j)
            xv[j] = Xw[(kg * 8 + j) * 32 + nt * 16 + lr];
#pragma unroll
        for (int j = 0; j < 8; ++j) {
            ushort h = f2bf(xv[j]);
            bh[nt][j] = (short)h;
            bl[nt][j] = (short)f2bf(xv[j] - bf2f(h));
        }
    }
}

// ---------------- QKV projection v12: software-pipelined (conv || MFMA) ------
// Block = 4 waves; wave = 64 out x 32 px, K = 256 in 8 chunks of 32c.
// Per iter kc: issue A(kc) reg-loads -> issue gl16 X(kc+2) -> vmcnt(12)
// (drains ONLY X(kc+1); A + new stage stay in flight) -> ds_read+convert
// B(kc+1) [covers A's L2 latency] -> MFMA(kc). One asm wait per iter; NO
// sched_barrier so the compiler interleaves conversions (VALU) with MFMA.
// X(k) lives in LDS buf k&1; staged 2 chunks ahead. B regs double-buffered
// by kc parity (compile-time under full unroll).
// Same fragment maps + per-acc MFMA order as v6-v11 -> bitwise-identical out.
__global__ __launch_bounds__(256) void k_qkv(
    const float* __restrict__ q_in, const float* __restrict__ kv_in,
    const ushort* __restrict__ WfQh, const ushort* __restrict__ WfQl,
    const ushort* __restrict__ WfKVh, const ushort* __restrict__ WfKVl,
    float* __restrict__ qh, float* __restrict__ kh, float* __restrict__ vv)
{
    __shared__ float Xl[2][4][32 * 32];    // [buf][wave][c*32+px] = 32 KB

    int bid  = blockIdx.x;
    int g    = bid / 3;
    int role = bid - g * 3;                // 0=Q 1=K 2=V
    int b    = g >> 7;                     // batch (128 groups per batch)
    int p0   = (g & 127) * 128;            // pixel base within batch

    const float*  xsrc = (role == 0) ? q_in : kv_in;
    const ushort* Wh = (role == 0) ? WfQh : (role == 1) ? WfKVh : (WfKVh + 16384);
    const ushort* Wl = (role == 0) ? WfQl : (role == 1) ? WfKVl : (WfKVl + 16384);
    float* outp = (role == 0) ? qh : (role == 1) ? kh : vv;
    bool norm = (role < 2);                // uniform per block

    int tid  = threadIdx.x;
    int lane = tid & 63;
    int wid  = __builtin_amdgcn_readfirstlane(tid >> 6);
    int lr = lane & 15, kg = lane >> 4;

    const float* xw = xsrc + ((size_t)b * DIM_ << 14) + p0 + wid * 32;

    // ---- prologue: stage X(0)->buf0, X(1)->buf1; convert B(0)
#pragma unroll
    for (int i = 0; i < 4; ++i) {
        int s = i * 64 + lane;             // r = s>>3 (c-row), seg = s&7
        gl16(xw + (size_t)(s >> 3) * HW_ + (s & 7) * 4, &Xl[0][wid][s * 4]);
    }
#pragma unroll
    for (int i = 0; i < 4; ++i) {
        int s = i * 64 + lane;
        gl16(xw + (size_t)(32 + (s >> 3)) * HW_ + (s & 7) * 4, &Xl[1][wid][s * 4]);
    }
    asm volatile("s_waitcnt vmcnt(4)" ::: "memory");   // X(0) landed, X(1) in flight

    short8 BH[2][2], BL[2][2];             // [kc&1][nt]
    conv_b(&Xl[0][wid][0], lr, kg, BH[0], BL[0]);

    f32x4 acc[4][2];
#pragma unroll
    for (int mt = 0; mt < 4; ++mt)
#pragma unroll
        for (int nt = 0; nt < 2; ++nt) {
            f32x4 z = {0.f, 0.f, 0.f, 0.f};
            acc[mt][nt] = z;
        }

#pragma unroll
    for (int kc = 0; kc < 8; ++kc) {
        const int cs = kc & 1;             // current B set; also X(kc+2)'s buf

        // A(kc) reg loads (16B coalesced, L2-hot); compiler waits right
        // before the MFMAs that use them (late vmcnt ~4)
        short8 ah[4], al[4];
#pragma unroll
        for (int mt = 0; mt < 4; ++mt) {
            ah[mt] = *(const short8*)(Wh + (((mt * 8 + kc) << 6) + lane) * 8);
            al[mt] = *(const short8*)(Wl + (((mt * 8 + kc) << 6) + lane) * 8);
        }

        if (kc < 6) {                      // stage X(kc+2) -> buf kc&1
#pragma unroll
            for (int i = 0; i < 4; ++i) {
                int s = i * 64 + lane;
                gl16(xw + (size_t)((kc + 2) * 32 + (s >> 3)) * HW_ + (s & 7) * 4,
                     &Xl[cs][wid][s * 4]);
            }
            // drain exactly X(kc+1) (4 oldest); keep A(kc)[8] + X(kc+2)[4]
            asm volatile("s_waitcnt vmcnt(12)" ::: "memory");
        } else if (kc == 6) {
            // in flight: X(7)[4] + A(6)[8]; drain X(7)
            asm volatile("s_waitcnt vmcnt(8)" ::: "memory");
        }

        if (kc < 7)                        // convert B(kc+1) (overlaps MFMA(kc))
            conv_b(&Xl[(kc + 1) & 1][wid][0], lr, kg, BH[cs ^ 1], BL[cs ^ 1]);

#pragma unroll
        for (int mt = 0; mt < 4; ++mt)
#pragma unroll
            for (int nt = 0; nt < 2; ++nt) {
                acc[mt][nt] = __builtin_amdgcn_mfma_f32_16x16x32_bf16(ah[mt], BH[cs][nt], acc[mt][nt], 0, 0, 0);
                acc[mt][nt] = __builtin_amdgcn_mfma_f32_16x16x32_bf16(ah[mt], BL[cs][nt], acc[mt][nt], 0, 0, 0);
                acc[mt][nt] = __builtin_amdgcn_mfma_f32_16x16x32_bf16(al[mt], BH[cs][nt], acc[mt][nt], 0, 0, 0);
            }
    }

    // ---- epilogue: l2norm + store
    int pr = p0 + wid * 32;
#pragma unroll
    for (int mt = 0; mt < 4; ++mt) {
#pragma unroll
        for (int nt = 0; nt < 2; ++nt) {
            f32x4 v = acc[mt][nt];
            if (norm) {                    // l2norm over the head's 16 rows
                float s = v.x * v.x + v.y * v.y + v.z * v.z + v.w * v.w;
                s += __shfl_xor(s, 16);    // lanes {lr, lr+16, lr+32, lr+48}
                s += __shfl_xor(s, 32);
                float inv = 1.f / fmaxf(sqrtf(s), 1e-12f);
                v.x *= inv; v.y *= inv; v.z *= inv; v.w *= inv;
            }
            float* dst = outp
                + (((size_t)(b * HEADS_ + mt) << 14) + pr + nt * 16 + lr) * HD_ + kg * 4;
            *(f32x4*)dst = v;
        }
    }
}

__device__ __forceinline__ int refl(int i, int n) {
    if (i < 0) i = -i;
    if (i >= n) i = 2 * n - 2 - i;
    return i;
}

// ---------------- sliding-window attention v7: split-d pair + XCD swizzle ----
__global__ __launch_bounds__(256) void k_attn(
    const float* __restrict__ qh, const float* __restrict__ kh,
    const float* __restrict__ vv, float* __restrict__ ao)
{
    int bid = blockIdx.x;
    int swz = (bid & 7) * 256 + (bid >> 3);          // bijective on 2048
    int tid = threadIdx.x;
    int lane = tid & 63;
    int wv  = tid >> 6;                              // 0..3
    int t   = lane >> 5;                             // d-half: 0 or 1
    int pl  = lane & 31;

    int pix = swz * 128 + wv * 32 + pl;              // (bh*HW + p), 0..262143
    int p  = pix & (HW_ - 1);
    int bh = pix >> 14;
    int y = p >> 7, x = p & (W_ - 1);
    int to = t * 8;

    const float* qp = qh + ((size_t)bh * HW_ + p) * HD_ + to;
    float4 qa = *(const float4*)(qp + 0);
    float4 qb = *(const float4*)(qp + 4);

    float logit[WS_ * WS_];
    int   nidx [WS_ * WS_];
#pragma unroll
    for (int i = 0; i < WS_; ++i) {
        int ry = refl(y + i - PAD_, H_);
#pragma unroll
        for (int j = 0; j < WS_; ++j) {
            int rx = refl(x + j - PAD_, W_);
            int np_ = ry * W_ + rx;
            nidx[i*WS_ + j] = np_;
            const float* kp = kh + ((size_t)bh * HW_ + np_) * HD_ + to;
            float4 ka = *(const float4*)(kp + 0);
            float4 kb = *(const float4*)(kp + 4);
            float d = 0.f;
            d = fmaf(qa.x, ka.x, d); d = fmaf(qa.y, ka.y, d);
            d = fmaf(qa.z, ka.z, d); d = fmaf(qa.w, ka.w, d);
            d = fmaf(qb.x, kb.x, d); d = fmaf(qb.y, kb.y, d);
            d = fmaf(qb.z, kb.z, d); d = fmaf(qb.w, kb.w, d);
            logit[i*WS_ + j] = d + __shfl_xor(d, 32);   // combine d-halves
        }
    }

    float m = logit[0];
#pragma unroll
    for (int w = 1; w < WS_*WS_; ++w) m = fmaxf(m, logit[w]);
    float s = 0.f;
#pragma unroll
    for (int w = 0; w < WS_*WS_; ++w) { float e = expf(logit[w] - m); logit[w] = e; s += e; }
    float invs = 1.f / s;

    float a[8];
#pragma unroll
    for (int d = 0; d < 8; ++d) a[d] = 0.f;
#pragma unroll
    for (int w = 0; w < WS_*WS_; ++w) {
        float wt = logit[w] * invs;
        const float* vp = vv + ((size_t)bh * HW_ + nidx[w]) * HD_ + to;
        float4 va = *(const float4*)(vp + 0);
        float4 vb = *(const float4*)(vp + 4);
        a[0] = fmaf(wt, va.x, a[0]); a[1] = fmaf(wt, va.y, a[1]);
        a[2] = fmaf(wt, va.z, a[2]); a[3] = fmaf(wt, va.w, a[3]);
        a[4] = fmaf(wt, vb.x, a[4]); a[5] = fmaf(wt, vb.y, a[5]);
        a[6] = fmaf(wt, vb.z, a[6]); a[7] = fmaf(wt, vb.w, a[7]);
    }

    int b = bh >> 2, h = bh & 3;
    float* aop = ao + ((size_t)b * HW_ + p) * AD_ + h * HD_ + to;
    *(float4*)(aop + 0) = make_float4(a[0], a[1], a[2], a[3]);
    *(float4*)(aop + 4) = make_float4(a[4], a[5], a[6], a[7]);
}

// ---------------- output projection v2: MFMA bf16x3 --------------------------
// GEMM: out[256 oc][65536 px] = Wo(256x64) . ao^T(64 x px). B operand
// (ao[p][c]) is lane-contiguous -> no LDS. Block = 4 waves over the SAME
// 16 pixels; wave wid owns oc [wid*64, wid*64+64) = 4 m-tiles. K=64 in 2
// chunks. D layout: col = lane&15 = px, row = 4*(lane>>4)+reg = oc-in-tile.
__global__ __launch_bounds__(256) void k_oproj(
    const float* __restrict__ ao, const ushort* __restrict__ WoFh,
    const ushort* __restrict__ WoFl, float* __restrict__ out)
{
    int tid  = threadIdx.x;
    int lane = tid & 63;
    int wid  = __builtin_amdgcn_readfirstlane(tid >> 6);  // oc quarter
    int lr = lane & 15, kg = lane >> 4;
    int pix = blockIdx.x * 16 + lr;       // this lane's pixel column
    int b = pix >> 14;
    int p = pix & (HW_ - 1);

    f32x4 acc[4];
#pragma unroll
    for (int mt = 0; mt < 4; ++mt) { f32x4 z = {0.f,0.f,0.f,0.f}; acc[mt] = z; }

#pragma unroll
    for (int kc = 0; kc < 2; ++kc) {
        const float* bp = ao + (size_t)pix * AD_ + kc * 32 + kg * 8;
        float4 x0 = *(const float4*)(bp + 0);
        float4 x1 = *(const float4*)(bp + 4);
        float xv[8] = {x0.x, x0.y, x0.z, x0.w, x1.x, x1.y, x1.z, x1.w};
        short8 bh, bl;
#pragma unroll
        for (int j = 0; j < 8; ++j) {
            ushort h = f2bf(xv[j]);
            bh[j] = (short)h;
            bl[j] = (short)f2bf(xv[j] - bf2f(h));
        }
#pragma unroll
        for (int mt = 0; mt < 4; ++mt) {
            int mtg = wid * 4 + mt;       // global 16-oc tile, 0..15
            short8 ah = *(const short8*)(WoFh + (((mtg * 2 + kc) << 6) + lane) * 8);
            short8 al = *(const short8*)(WoFl + (((mtg * 2 + kc) << 6) + lane) * 8);
            acc[mt] = __builtin_amdgcn_mfma_f32_16x16x32_bf16(ah, bh, acc[mt], 0, 0, 0);
            acc[mt] = __builtin_amdgcn_mfma_f32_16x16x32_bf16(ah, bl, acc[mt], 0, 0, 0);
            acc[mt] = __builtin_amdgcn_mfma_f32_16x16x32_bf16(al, bh, acc[mt], 0, 0, 0);
        }
    }

#pragma unroll
    for (int mt = 0; mt < 4; ++mt) {
        int oc = wid * 64 + mt * 16 + kg * 4;
        float* op = out + (size_t)b * DIM_ * HW_ + (size_t)oc * HW_ + p;
        op[0 * HW_] = acc[mt].x;
        op[1 * HW_] = acc[mt].y;
        op[2 * HW_] = acc[mt].z;
        op[3 * HW_] = acc[mt].w;
    }
}

extern "C" void kernel_launch(void* const* d_in, const int* in_sizes, int n_in,
                              void* d_out, int out_size, void* d_ws, size_t ws_size,
                              hipStream_t stream) {
    const float* q_in  = (const float*)d_in[0];
    const float* kv_in = (const float*)d_in[1];
    const float* Wq    = (const float*)d_in[2];
    const float* Wk    = (const float*)d_in[3];
    const float* Wv    = (const float*)d_in[4];
    const float* Wo    = (const float*)d_in[5];
    float* out = (float*)d_out;

    float* wsf = (float*)d_ws;
    ushort* u     = (ushort*)wsf;
    ushort* WfQh  = u;             // 16384 shorts
    ushort* WfQl  = u + 16384;     // 16384
    ushort* WfKVh = u + 32768;     // 32768 (K: first 16384, V: last 16384)
    ushort* WfKVl = u + 65536;     // 32768
    ushort* WoFh  = u + 98304;     // 16384
    ushort* WoFl  = u + 114688;    // 16384 (ends 131072 sh = 65536 floats)
    size_t tens = (size_t)B_ * HEADS_ * HW_ * HD_;   // 4,194,304 floats
    float* qh = wsf + 65536;
    float* kh = qh + tens;
    float* vv = kh + tens;
    float* ao = vv + tens;

    k_prep<<<dim3(192), dim3(256), 0, stream>>>(Wq, Wk, Wv, Wo,
                                                WfQh, WfQl, WfKVh, WfKVl, WoFh, WoFl);
    k_qkv<<<dim3(1536), dim3(256), 0, stream>>>(q_in, kv_in,
                                                WfQh, WfQl, WfKVh, WfKVl, qh, kh, vv);
    k_attn <<<dim3(2048), dim3(256), 0, stream>>>(qh, kh, vv, ao);
    k_oproj<<<dim3(4096), dim3(256), 0, stream>>>(ao, WoFh, WoFl, out);
}

// Round 13
// 122.426 us; speedup vs baseline: 1.9196x; 1.0060x over previous
//
#include <hip/hip_runtime.h>
#include <hip/hip_bf16.h>
#include <math.h>

#define B_ 4
#define DIM_ 256
#define H_ 128
#define W_ 128
#define HW_ (H_ * W_)
#define AD_ 64
#define HEADS_ 4
#define HD_ 16
#define WS_ 5
#define PAD_ 2

typedef __attribute__((ext_vector_type(8))) short short8;
typedef __attribute__((ext_vector_type(4))) float f32x4;
typedef __attribute__((ext_vector_type(4))) unsigned int u32x4;

__device__ __forceinline__ ushort f2bf(float f) {
    unsigned u = __builtin_bit_cast(unsigned, f);
    unsigned r = u + 0x7FFFu + ((u >> 16) & 1u);
    return (ushort)(r >> 16);
}
__device__ __forceinline__ float bf2f(ushort h) {
    return __builtin_bit_cast(float, (unsigned)h << 16);
}

// Truncation-based hi/lo split of an f32 pair into packed bf16 pairs.
// hi = top 16 bits (truncate); lo = truncate(x - hi). Residual error
// ~2^-16 relative (same class as RTNE split; lo absorbs hi's round-off).
// 6 VALU ops per 2 elements vs ~17 for the manual-RTNE version.
__device__ __forceinline__ void splitpair(float x0, float x1,
                                          unsigned& hp, unsigned& lp) {
    unsigned u0 = __builtin_bit_cast(unsigned, x0);
    unsigned u1 = __builtin_bit_cast(unsigned, x1);
    hp = __builtin_amdgcn_perm(u1, u0, 0x07060302u);   // [u0.hi16, u1.hi16]
    float r0 = x0 - __builtin_bit_cast(float, u0 & 0xFFFF0000u);
    float r1 = x1 - __builtin_bit_cast(float, u1 & 0xFFFF0000u);
    lp = __builtin_amdgcn_perm(__builtin_bit_cast(unsigned, r1),
                               __builtin_bit_cast(unsigned, r0), 0x07060302u);
}

// async global->LDS, 16B per lane. LDS dest must be wave-uniform base + lane*16.
__device__ __forceinline__ void gl16(const void* g, void* l) {
    __builtin_amdgcn_global_load_lds(
        (const __attribute__((address_space(1))) unsigned int*)g,
        (__attribute__((address_space(3))) unsigned int*)l, 16, 0, 0);
}

// ---------------- prep: fragment-ordered bf16 hi/lo weights (Q/K/V/O) --------
// A-fragment layout for mfma_f32_16x16x32_bf16: lane l holds A[o=l&15][c] for
// 8 c's = kc*32 + (l>>4)*8 + j. The SAME (lane,j)->c map is used for every B
// path, so each contraction is correct under a consistent k-perm.
__global__ __launch_bounds__(256) void k_prep(
    const float* __restrict__ Wq, const float* __restrict__ Wk,
    const float* __restrict__ Wv, const float* __restrict__ Wo,
    ushort* __restrict__ WfQh, ushort* __restrict__ WfQl,
    ushort* __restrict__ WfKVh, ushort* __restrict__ WfKVl,
    ushort* __restrict__ WoFh, ushort* __restrict__ WoFl)
{
    int i = blockIdx.x * 256 + threadIdx.x;          // 0 .. 49151
    if (i < 16384) {                                 // Q frags: 4mt*8kc*64l*8j
        int j = i & 7, l = (i >> 3) & 63, kc = (i >> 9) & 7, mt = i >> 12;
        int o = mt * 16 + (l & 15);
        int c = kc * 32 + ((l >> 4) & 3) * 8 + j;
        float wv = Wq[o * DIM_ + c];
        ushort h = f2bf(wv);
        WfQh[i] = h;
        WfQl[i] = f2bf(wv - bf2f(h));
        // Wo frags: 16 mtg * 2 kc * 64 l * 8 j (K=64)
        int kco = (i >> 9) & 1, mtg = i >> 10;
        int oo = mtg * 16 + (l & 15);                // Wo row (out channel)
        int co = kco * 32 + ((l >> 4) & 3) * 8 + j;  // Wo col (attn channel)
        float wo = Wo[oo * AD_ + co];
        ushort ho = f2bf(wo);
        WoFh[i] = ho;
        WoFl[i] = f2bf(wo - bf2f(ho));
    } else if (i < 49152) {                          // KV frags: 8mt (K:0-3, V:4-7)
        int ii = i - 16384;
        int j = ii & 7, l = (ii >> 3) & 63, kc = (ii >> 9) & 7, mt = ii >> 12;
        const float* Ws = (mt < 4) ? Wk : Wv;
        int o = (mt & 3) * 16 + (l & 15);
        int c = kc * 32 + ((l >> 4) & 3) * 8 + j;
        float wv = Ws[o * DIM_ + c];
        ushort h = f2bf(wv);
        WfKVh[ii] = h;
        WfKVl[ii] = f2bf(wv - bf2f(h));
    }
}

// convert one 32c x (2x16px) B tile from this wave's LDS X subtile
// (truncation split: ~3 VALU ops/element)
__device__ __forceinline__ void conv_b(const float* Xw, int lr, int kg,
                                       short8* bh, short8* bl)
{
#pragma unroll
    for (int nt = 0; nt < 2; ++nt) {
        u32x4 h, l;
#pragma unroll
        for (int jp = 0; jp < 4; ++jp) {
            float x0 = Xw[(kg * 8 + 2 * jp    ) * 32 + nt * 16 + lr];
            float x1 = Xw[(kg * 8 + 2 * jp + 1) * 32 + nt * 16 + lr];
            unsigned hp, lp;
            splitpair(x0, x1, hp, lp);
            h[jp] = hp;
            l[jp] = lp;
        }
        bh[nt] = __builtin_bit_cast(short8, h);
        bl[nt] = __builtin_bit_cast(short8, l);
    }
}

// ---------------- QKV projection v13: R11 structure + cheap split ------------
// Block = 4 waves; wave = 64 out x 32 px, K = 256 in 8 chunks of 32c.
//  - X: per-WAVE-private LDS subtile [2][32c][32px] (32 KB/block).
//  - A-frags: direct global->VGPR 16B loads (coalesced, L2-hot 96 KB).
//  - NO __syncthreads. Per wave: A-loads, then 4 gl16 for the NEXT chunk,
//    then s_waitcnt vmcnt(4) (drains this chunk's staged X + the A stream,
//    keeps the 4 new gl16s in flight) + sched_barrier (rule #18).
//  - B conversion uses the truncation split (~3x fewer VALU ops than R11).
__global__ __launch_bounds__(256) void k_qkv(
    const float* __restrict__ q_in, const float* __restrict__ kv_in,
    const ushort* __restrict__ WfQh, const ushort* __restrict__ WfQl,
    const ushort* __restrict__ WfKVh, const ushort* __restrict__ WfKVl,
    float* __restrict__ qh, float* __restrict__ kh, float* __restrict__ vv)
{
    __shared__ float Xl[2][4][32 * 32];    // [buf][wave][c*32+px] = 32 KB

    int bid  = blockIdx.x;
    int g    = bid / 3;
    int role = bid - g * 3;                // 0=Q 1=K 2=V
    int b    = g >> 7;                     // batch (128 groups per batch)
    int p0   = (g & 127) * 128;            // pixel base within batch

    const float*  xsrc = (role == 0) ? q_in : kv_in;
    const ushort* Wh = (role == 0) ? WfQh : (role == 1) ? WfKVh : (WfKVh + 16384);
    const ushort* Wl = (role == 0) ? WfQl : (role == 1) ? WfKVl : (WfKVl + 16384);
    float* outp = (role == 0) ? qh : (role == 1) ? kh : vv;
    bool norm = (role < 2);                // uniform per block

    int tid  = threadIdx.x;
    int lane = tid & 63;
    int wid  = __builtin_amdgcn_readfirstlane(tid >> 6);
    int lr = lane & 15, kg = lane >> 4;

    const float* xw = xsrc + ((size_t)b * DIM_ << 14) + p0 + wid * 32;

    // ---- prologue: stage chunk 0 into buf 0 (per wave: 4 gl16)
#pragma unroll
    for (int i = 0; i < 4; ++i) {
        int s = i * 64 + lane;             // r = s>>3 (c-row), seg = s&7
        gl16(xw + (size_t)(s >> 3) * HW_ + (s & 7) * 4, &Xl[0][wid][s * 4]);
    }

    f32x4 acc[4][2];
#pragma unroll
    for (int mt = 0; mt < 4; ++mt)
#pragma unroll
        for (int nt = 0; nt < 2; ++nt) {
            f32x4 z = {0.f, 0.f, 0.f, 0.f};
            acc[mt][nt] = z;
        }

    for (int kc = 0; kc < 8; ++kc) {
        int buf = kc & 1;

        // A-frag register loads for THIS chunk (issue before staging so the
        // vmcnt(4) below leaves only the new gl16s in flight)
        short8 ah[4], al[4];
#pragma unroll
        for (int mt = 0; mt < 4; ++mt) {
            ah[mt] = *(const short8*)(Wh + (((mt * 8 + kc) << 6) + lane) * 8);
            al[mt] = *(const short8*)(Wl + (((mt * 8 + kc) << 6) + lane) * 8);
        }

        if (kc < 7) {                      // stage chunk kc+1 -> other buf
#pragma unroll
            for (int i = 0; i < 4; ++i) {
                int s = i * 64 + lane;
                gl16(xw + (size_t)((kc + 1) * 32 + (s >> 3)) * HW_ + (s & 7) * 4,
                     &Xl[buf ^ 1][wid][s * 4]);
            }
        }

        // prev-chunk gl16s (this buf) have landed; 4 newest stay in flight
        asm volatile("s_waitcnt vmcnt(4)" ::: "memory");
        __builtin_amdgcn_sched_barrier(0);

        // ---- compute current chunk from this wave's private LDS tile
        short8 bh[2], bl[2];
        conv_b(&Xl[buf][wid][0], lr, kg, bh, bl);
#pragma unroll
        for (int mt = 0; mt < 4; ++mt) {
#pragma unroll
            for (int nt = 0; nt < 2; ++nt) {
                acc[mt][nt] = __builtin_amdgcn_mfma_f32_16x16x32_bf16(ah[mt], bh[nt], acc[mt][nt], 0, 0, 0);
                acc[mt][nt] = __builtin_amdgcn_mfma_f32_16x16x32_bf16(ah[mt], bl[nt], acc[mt][nt], 0, 0, 0);
                acc[mt][nt] = __builtin_amdgcn_mfma_f32_16x16x32_bf16(al[mt], bh[nt], acc[mt][nt], 0, 0, 0);
            }
        }
        // no barrier: X tile is wave-private; lgkm waits order ds_read vs reuse
    }

    // ---- epilogue: l2norm + store
    int pr = p0 + wid * 32;
#pragma unroll
    for (int mt = 0; mt < 4; ++mt) {
#pragma unroll
        for (int nt = 0; nt < 2; ++nt) {
            f32x4 v = acc[mt][nt];
            if (norm) {                    // l2norm over the head's 16 rows
                float s = v.x * v.x + v.y * v.y + v.z * v.z + v.w * v.w;
                s += __shfl_xor(s, 16);    // lanes {lr, lr+16, lr+32, lr+48}
                s += __shfl_xor(s, 32);
                float inv = 1.f / fmaxf(sqrtf(s), 1e-12f);
                v.x *= inv; v.y *= inv; v.z *= inv; v.w *= inv;
            }
            float* dst = outp
                + (((size_t)(b * HEADS_ + mt) << 14) + pr + nt * 16 + lr) * HD_ + kg * 4;
            *(f32x4*)dst = v;
        }
    }
}

__device__ __forceinline__ int refl(int i, int n) {
    if (i < 0) i = -i;
    if (i >= n) i = 2 * n - 2 - i;
    return i;
}

// ---------------- sliding-window attention v7: split-d pair + XCD swizzle ----
__global__ __launch_bounds__(256) void k_attn(
    const float* __restrict__ qh, const float* __restrict__ kh,
    const float* __restrict__ vv, float* __restrict__ ao)
{
    int bid = blockIdx.x;
    int swz = (bid & 7) * 256 + (bid >> 3);          // bijective on 2048
    int tid = threadIdx.x;
    int lane = tid & 63;
    int wv  = tid >> 6;                              // 0..3
    int t   = lane >> 5;                             // d-half: 0 or 1
    int pl  = lane & 31;

    int pix = swz * 128 + wv * 32 + pl;              // (bh*HW + p), 0..262143
    int p  = pix & (HW_ - 1);
    int bh = pix >> 14;
    int y = p >> 7, x = p & (W_ - 1);
    int to = t * 8;

    const float* qp = qh + ((size_t)bh * HW_ + p) * HD_ + to;
    float4 qa = *(const float4*)(qp + 0);
    float4 qb = *(const float4*)(qp + 4);

    float logit[WS_ * WS_];
    int   nidx [WS_ * WS_];
#pragma unroll
    for (int i = 0; i < WS_; ++i) {
        int ry = refl(y + i - PAD_, H_);
#pragma unroll
        for (int j = 0; j < WS_; ++j) {
            int rx = refl(x + j - PAD_, W_);
            int np_ = ry * W_ + rx;
            nidx[i*WS_ + j] = np_;
            const float* kp = kh + ((size_t)bh * HW_ + np_) * HD_ + to;
            float4 ka = *(const float4*)(kp + 0);
            float4 kb = *(const float4*)(kp + 4);
            float d = 0.f;
            d = fmaf(qa.x, ka.x, d); d = fmaf(qa.y, ka.y, d);
            d = fmaf(qa.z, ka.z, d); d = fmaf(qa.w, ka.w, d);
            d = fmaf(qb.x, kb.x, d); d = fmaf(qb.y, kb.y, d);
            d = fmaf(qb.z, kb.z, d); d = fmaf(qb.w, kb.w, d);
            logit[i*WS_ + j] = d + __shfl_xor(d, 32);   // combine d-halves
        }
    }

    float m = logit[0];
#pragma unroll
    for (int w = 1; w < WS_*WS_; ++w) m = fmaxf(m, logit[w]);
    float s = 0.f;
#pragma unroll
    for (int w = 0; w < WS_*WS_; ++w) { float e = expf(logit[w] - m); logit[w] = e; s += e; }
    float invs = 1.f / s;

    float a[8];
#pragma unroll
    for (int d = 0; d < 8; ++d) a[d] = 0.f;
#pragma unroll
    for (int w = 0; w < WS_*WS_; ++w) {
        float wt = logit[w] * invs;
        const float* vp = vv + ((size_t)bh * HW_ + nidx[w]) * HD_ + to;
        float4 va = *(const float4*)(vp + 0);
        float4 vb = *(const float4*)(vp + 4);
        a[0] = fmaf(wt, va.x, a[0]); a[1] = fmaf(wt, va.y, a[1]);
        a[2] = fmaf(wt, va.z, a[2]); a[3] = fmaf(wt, va.w, a[3]);
        a[4] = fmaf(wt, vb.x, a[4]); a[5] = fmaf(wt, vb.y, a[5]);
        a[6] = fmaf(wt, vb.z, a[6]); a[7] = fmaf(wt, vb.w, a[7]);
    }

    int b = bh >> 2, h = bh & 3;
    float* aop = ao + ((size_t)b * HW_ + p) * AD_ + h * HD_ + to;
    *(float4*)(aop + 0) = make_float4(a[0], a[1], a[2], a[3]);
    *(float4*)(aop + 4) = make_float4(a[4], a[5], a[6], a[7]);
}

// ---------------- output projection v2: MFMA bf16x3 --------------------------
// GEMM: out[256 oc][65536 px] = Wo(256x64) . ao^T(64 x px). B operand
// (ao[p][c]) is lane-contiguous -> no LDS. Block = 4 waves over the SAME
// 16 pixels; wave wid owns oc [wid*64, wid*64+64) = 4 m-tiles. K=64 in 2
// chunks. D layout: col = lane&15 = px, row = 4*(lane>>4)+reg = oc-in-tile.
__global__ __launch_bounds__(256) void k_oproj(
    const float* __restrict__ ao, const ushort* __restrict__ WoFh,
    const ushort* __restrict__ WoFl, float* __restrict__ out)
{
    int tid  = threadIdx.x;
    int lane = tid & 63;
    int wid  = __builtin_amdgcn_readfirstlane(tid >> 6);  // oc quarter
    int lr = lane & 15, kg = lane >> 4;
    int pix = blockIdx.x * 16 + lr;       // this lane's pixel column
    int b = pix >> 14;
    int p = pix & (HW_ - 1);

    f32x4 acc[4];
#pragma unroll
    for (int mt = 0; mt < 4; ++mt) { f32x4 z = {0.f,0.f,0.f,0.f}; acc[mt] = z; }

#pragma unroll
    for (int kc = 0; kc < 2; ++kc) {
        const float* bp = ao + (size_t)pix * AD_ + kc * 32 + kg * 8;
        float4 x0 = *(const float4*)(bp + 0);
        float4 x1 = *(const float4*)(bp + 4);
        float xv[8] = {x0.x, x0.y, x0.z, x0.w, x1.x, x1.y, x1.z, x1.w};
        u32x4 hh, ll;
#pragma unroll
        for (int jp = 0; jp < 4; ++jp) {
            unsigned hp, lp;
            splitpair(xv[2 * jp], xv[2 * jp + 1], hp, lp);
            hh[jp] = hp;
            ll[jp] = lp;
        }
        short8 bh = __builtin_bit_cast(short8, hh);
        short8 bl = __builtin_bit_cast(short8, ll);
#pragma unroll
        for (int mt = 0; mt < 4; ++mt) {
            int mtg = wid * 4 + mt;       // global 16-oc tile, 0..15
            short8 ah = *(const short8*)(WoFh + (((mtg * 2 + kc) << 6) + lane) * 8);
            short8 al = *(const short8*)(WoFl + (((mtg * 2 + kc) << 6) + lane) * 8);
            acc[mt] = __builtin_amdgcn_mfma_f32_16x16x32_bf16(ah, bh, acc[mt], 0, 0, 0);
            acc[mt] = __builtin_amdgcn_mfma_f32_16x16x32_bf16(ah, bl, acc[mt], 0, 0, 0);
            acc[mt] = __builtin_amdgcn_mfma_f32_16x16x32_bf16(al, bh, acc[mt], 0, 0, 0);
        }
    }

#pragma unroll
    for (int mt = 0; mt < 4; ++mt) {
        int oc = wid * 64 + mt * 16 + kg * 4;
        float* op = out + (size_t)b * DIM_ * HW_ + (size_t)oc * HW_ + p;
        op[0 * HW_] = acc[mt].x;
        op[1 * HW_] = acc[mt].y;
        op[2 * HW_] = acc[mt].z;
        op[3 * HW_] = acc[mt].w;
    }
}

extern "C" void kernel_launch(void* const* d_in, const int* in_sizes, int n_in,
                              void* d_out, int out_size, void* d_ws, size_t ws_size,
                              hipStream_t stream) {
    const float* q_in  = (const float*)d_in[0];
    const float* kv_in = (const float*)d_in[1];
    const float* Wq    = (const float*)d_in[2];
    const float* Wk    = (const float*)d_in[3];
    const float* Wv    = (const float*)d_in[4];
    const float* Wo    = (const float*)d_in[5];
    float* out = (float*)d_out;

    float* wsf = (float*)d_ws;
    ushort* u     = (ushort*)wsf;
    ushort* WfQh  = u;             // 16384 shorts
    ushort* WfQl  = u + 16384;     // 16384
    ushort* WfKVh = u + 32768;     // 32768 (K: first 16384, V: last 16384)
    ushort* WfKVl = u + 65536;     // 32768
    ushort* WoFh  = u + 98304;     // 16384
    ushort* WoFl  = u + 114688;    // 16384 (ends 131072 sh = 65536 floats)
    size_t tens = (size_t)B_ * HEADS_ * HW_ * HD_;   // 4,194,304 floats
    float* qh = wsf + 65536;
    float* kh = qh + tens;
    float* vv = kh + tens;
    float* ao = vv + tens;

    k_prep<<<dim3(192), dim3(256), 0, stream>>>(Wq, Wk, Wv, Wo,
                                                WfQh, WfQl, WfKVh, WfKVl, WoFh, WoFl);
    k_qkv<<<dim3(1536), dim3(256), 0, stream>>>(q_in, kv_in,
                                                WfQh, WfQl, WfKVh, WfKVl, qh, kh, vv);
    k_attn <<<dim3(2048), dim3(256), 0, stream>>>(qh, kh, vv, ao);
    k_oproj<<<dim3(4096), dim3(256), 0, stream>>>(ao, WoFh, WoFl, out);
}